// Round 14
// baseline (361.157 us; speedup 1.0000x reference)
//
#include <hip/hip_runtime.h>
#include <hip/hip_bf16.h>
#include <stdint.h>

typedef unsigned short ushort_t;
typedef unsigned int uint_t;
typedef __attribute__((ext_vector_type(8))) short bfrag;   // 8 bf16 = 4 VGPR
typedef __attribute__((ext_vector_type(4))) float f32x4;

#define B_ 512
#define S_ 256
#define T_ 10
#define V_ 28
#define H_ 128

// ---- workspace layout (float element offsets) ----
#define XTD 0         // dec xg table [28][512]
#define XTG 14336     // enc xg gate-interleaved [2][28][128][4]
#define WTD 43008     // dec WhhT [128][512]
#define AWT 108544    // attn_WT [256][128]
#define OWT 141312    // out_WT [128][28]
#define PWT 144896    // projWT [256][128]
#define WPK 177664    // enc W_hi bf16 frag pack, 131072 ushort (K=128)
#define HFIN 308736
#define CFIN 439808
#define HDEC 570880
#define HS_BYTE_OFF (1226240ull * 4ull)
#define PREP_N 308736

__device__ __forceinline__ float fast_exp2(float x) { return __builtin_amdgcn_exp2f(x); }
__device__ __forceinline__ float fast_rcp(float x)  { return __builtin_amdgcn_rcpf(x); }
__device__ __forceinline__ float sigm(float x) {
    return fast_rcp(1.f + fast_exp2(-1.4426950408889634f * x));
}
__device__ __forceinline__ float tanh_(float x) {
    return 1.f - 2.f * fast_rcp(1.f + fast_exp2(2.8853900817779268f * x));
}
__device__ __forceinline__ ushort_t f2bf(float x) {
    uint_t u = __float_as_uint(x);
    return (ushort_t)((u + 0x7FFFu + ((u >> 16) & 1u)) >> 16);  // RNE
}
__device__ __forceinline__ float bflo(uint_t u) { return __uint_as_float(u << 16); }
__device__ __forceinline__ float bfhi(uint_t u) { return __uint_as_float(u & 0xFFFF0000u); }

// LDS-only barrier: drain LDS ops, sync, fence scheduler (rule #18).
__device__ __forceinline__ void lds_barrier() {
    asm volatile("s_waitcnt lgkmcnt(0)" ::: "memory");
    __builtin_amdgcn_s_barrier();
    __builtin_amdgcn_sched_barrier(0);
}

// ---------------- prep (unchanged) ----------------
__global__ __launch_bounds__(256) void prep_kernel(
    const float* __restrict__ embed,
    const float* __restrict__ Wih_f, const float* __restrict__ b_f,
    const float* __restrict__ Wih_b, const float* __restrict__ b_b,
    const float* __restrict__ Wih_d, const float* __restrict__ b_d,
    const float* __restrict__ Whh_f, const float* __restrict__ Whh_b,
    const float* __restrict__ Whh_d,
    const float* __restrict__ attn_W, const float* __restrict__ out_W,
    const float* __restrict__ proj_W,
    float* __restrict__ ws)
{
    int i = blockIdx.x * 256 + threadIdx.x;
    if (i < XTG) {                         // dec xg table: [v][j]
        int v = i >> 9, jj = i & 511;
        float acc = b_d[jj];
        #pragma unroll
        for (int e = 0; e < 32; ++e) acc = fmaf(embed[v * 32 + e], Wih_d[jj * 32 + e], acc);
        ws[XTD + i] = acc;
    } else if (i < WTD) {                  // enc xg gate-interleaved: [d][v][u][g]
        int r = i - XTG; int d = r / 14336; int rem = r % 14336;
        int v = rem >> 9, q = rem & 511;
        int uu = q >> 2, g = q & 3;
        int jj = g * 128 + uu;
        const float* Wih = d ? Wih_b : Wih_f;
        const float* bb  = d ? b_b   : b_f;
        float acc = bb[jj];
        #pragma unroll
        for (int e = 0; e < 32; ++e) acc = fmaf(embed[v * 32 + e], Wih[jj * 32 + e], acc);
        ws[XTG + r] = acc;
    } else if (i < AWT) {                  // dec WhhT[k][j]
        int r = i - WTD; int k = r >> 9, jj = r & 511;
        ws[WTD + r] = Whh_d[jj * 128 + k];
    } else if (i < OWT) {                  // attn_WT[k][u]
        int r = i - AWT; int k = r >> 7, uu = r & 127;
        ws[i] = attn_W[uu * 256 + k];
    } else if (i < PWT) {                  // out_WT[k][v]
        int r = i - OWT; int k = r / 28, v = r % 28;
        ws[i] = out_W[v * 128 + k];
    } else if (i < WPK) {                  // projWT[k][u]
        int r = i - PWT; int k = r >> 7, uu = r & 127;
        ws[i] = proj_W[uu * 256 + k];
    } else if (i < PREP_N) {               // enc W_hi frag pack, K=128 (pure bf16 hi)
        int i2 = (i - WPK) * 2;            // 2 ushorts per thread
        #pragma unroll
        for (int p = 0; p < 2; ++p, ++i2) {
            int e  = i2 & 7;
            int ll = (i2 >> 3) & 63;
            int kt = (i2 >> 9) & 3;
            int ni = (i2 >> 11) & 3;
            int wv = (i2 >> 13) & 7;
            int d  = (i2 >> 16) & 1;
            int jj = (ni * 8 + wv) * 16 + (ll & 15);   // gate column (N)
            int kp = kt * 32 + ((ll >> 4) << 3) + e;   // K index 0..127
            const float* Whh = d ? Whh_b : Whh_f;
            ((ushort_t*)(ws + WPK))[i2] = f2bf(Whh[jj * 128 + kp]);
        }
    }
}

// ---------------- encoder: MFMA K=128 bf16, rows at M={0,4,8,12}, in-lane cell ----------------
// VALU diet: zero-C MFMA start (no acc-init movs), xg added post-MFMA,
// incremental hs pointer.
__global__ __launch_bounds__(512, 2) void enc_kernel(
    const int* __restrict__ src,
    const float* __restrict__ xtg_base,     // ws+XTG
    const ushort_t* __restrict__ wpk,       // ws+WPK
    float* __restrict__ hfin, float* __restrict__ cfin,
    ushort_t* __restrict__ hs)
{
    const int bx = blockIdx.x;
    const int dir = bx >> 7;
    const int b0 = (bx & 127) << 2;
    const int tid = threadIdx.x;
    const int w = tid >> 6, l = tid & 63;
    const int lg = l >> 4, col = l & 15;
    const int u = (w << 4) + col;          // 0..127: this lane's hidden unit
    const int row = lg;                    // this lane's batch row (cell owner)

    __shared__ __align__(16) ushort_t hb[2][4][144];   // [buf][row][swizzled u], stride-padded
    __shared__ __align__(16) int tokl[256][4];         // [s][row]

    for (int i = tid; i < 1024; i += 512)
        tokl[i >> 2][i & 3] = src[(b0 + (i & 3)) * S_ + (i >> 2)];
    for (int i = tid; i < 576; i += 512) ((uint_t*)hb)[i] = 0u;

    const float* xtg = xtg_base + dir * 14336;

    // persistent B fragments: 4 N-tiles x 4 K-tiles = 64 regs
    bfrag bf[4][4];
    {
        const ushort_t* wb = wpk + (((size_t)dir * 8 + w) << 13) + l * 8;
        #pragma unroll
        for (int ni = 0; ni < 4; ++ni)
            #pragma unroll
            for (int kt = 0; kt < 4; ++kt)
                bf[ni][kt] = *reinterpret_cast<const bfrag*>(wb + ((ni * 4 + kt) << 9));
    }
    __syncthreads();

    float c_reg = 0.f, h_reg = 0.f;

    f32x4 xg_cur, xg_next;
    {
        int p0 = dir ? (S_ - 1) : 0;
        xg_cur = *reinterpret_cast<const f32x4*>(xtg + ((size_t)tokl[p0][row] << 9) + (u << 2));
    }

    // A fragments: A row = lane&15; real rows at M = {0,4,8,12}
    const bfrag zf = {0, 0, 0, 0, 0, 0, 0, 0};
    bfrag af0 = zf, af1 = zf, af2 = zf, af3 = zf;
    const bool ard = ((col & 3) == 0);
    const int ar = col >> 2;               // A-read row
    const int swz = ar << 3;
    const f32x4 zacc = {0.f, 0.f, 0.f, 0.f};

    // incremental hs pointer
    ushort_t* hs_ptr = hs + ((size_t)(b0 + row) * S_ + (dir ? (S_ - 1) : 0)) * 256
                          + dir * 128 + u;
    const int hs_step = dir ? -256 : 256;

    for (int t = 0; t < S_; ++t) {
        const int cb = t & 1, nb = cb ^ 1;

        // prefetch next step's xg (consumed next iteration)
        if (t + 1 < S_) {
            int pn = dir ? (S_ - 2 - t) : (t + 1);
            xg_next = *reinterpret_cast<const f32x4*>(xtg + ((size_t)tokl[pn][row] << 9) + (u << 2));
        }

        // masked A-frag reads: lanes col in {0,4,8,12}, XOR-swizzled
        if (ard) {
            const ushort_t* hp = &hb[cb][ar][0];
            af0 = *reinterpret_cast<const bfrag*>(hp + ((  0 + (lg << 3)) ^ swz));
            af1 = *reinterpret_cast<const bfrag*>(hp + (( 32 + (lg << 3)) ^ swz));
            af2 = *reinterpret_cast<const bfrag*>(hp + (( 64 + (lg << 3)) ^ swz));
            af3 = *reinterpret_cast<const bfrag*>(hp + (( 96 + (lg << 3)) ^ swz));
        }

        // K-tile 0 from zero-C (no acc init); K-tiles 1..3 accumulate
        f32x4 a0 = __builtin_amdgcn_mfma_f32_16x16x32_bf16(af0, bf[0][0], zacc, 0, 0, 0);
        f32x4 a1 = __builtin_amdgcn_mfma_f32_16x16x32_bf16(af0, bf[1][0], zacc, 0, 0, 0);
        f32x4 a2 = __builtin_amdgcn_mfma_f32_16x16x32_bf16(af0, bf[2][0], zacc, 0, 0, 0);
        f32x4 a3 = __builtin_amdgcn_mfma_f32_16x16x32_bf16(af0, bf[3][0], zacc, 0, 0, 0);
        #define KT1(AF, kt) { \
            a0 = __builtin_amdgcn_mfma_f32_16x16x32_bf16(AF, bf[0][kt], a0, 0, 0, 0); \
            a1 = __builtin_amdgcn_mfma_f32_16x16x32_bf16(AF, bf[1][kt], a1, 0, 0, 0); \
            a2 = __builtin_amdgcn_mfma_f32_16x16x32_bf16(AF, bf[2][kt], a2, 0, 0, 0); \
            a3 = __builtin_amdgcn_mfma_f32_16x16x32_bf16(AF, bf[3][kt], a3, 0, 0, 0); \
        }
        KT1(af1, 1) KT1(af2, 2) KT1(af3, 3)
        #undef KT1

        // cell: fully in-register, every lane owns one (row, u); xg added here
        {
            float gi = a0[0] + xg_cur[0], gf = a1[0] + xg_cur[1];
            float gg = a2[0] + xg_cur[2], go = a3[0] + xg_cur[3];
            float ii = sigm(gi), ff = sigm(gf), gG = tanh_(gg), oo = sigm(go);
            c_reg = ff * c_reg + ii * gG;
            float h = oo * tanh_(c_reg);
            h_reg = h;
            ushort_t hi = f2bf(h);
            hb[nb][row][u ^ (row << 3)] = hi;
            *hs_ptr = hi;
            hs_ptr += hs_step;
        }
        xg_cur = xg_next;
        lds_barrier();
    }

    hfin[dir * 65536 + (b0 + row) * 128 + u] = h_reg;
    cfin[dir * 65536 + (b0 + row) * 128 + u] = c_reg;
}

// ---------------- decoder LSTM only (unchanged) ----------------
__global__ __launch_bounds__(512, 1) void dec_lstm_kernel(
    const int* __restrict__ target,
    const float* __restrict__ xt_d,
    const float* __restrict__ WhhT_d,
    const float* __restrict__ hfin, const float* __restrict__ cfin,
    float* __restrict__ hdec)
{
    const int b0 = blockIdx.x * 2;
    const int tid = threadIdx.x;
    const int j = tid;

    __shared__ __align__(16) float h_lds[2][128];
    __shared__ __align__(16) float g_lds[2][512];

    float4 w4[32];
    #pragma unroll
    for (int kc = 0; kc < 32; ++kc) {
        w4[kc].x = WhhT_d[(kc * 4 + 0) * 512 + j];
        w4[kc].y = WhhT_d[(kc * 4 + 1) * 512 + j];
        w4[kc].z = WhhT_d[(kc * 4 + 2) * 512 + j];
        w4[kc].w = WhhT_d[(kc * 4 + 3) * 512 + j];
    }
    const int r1 = tid >> 7, u1 = tid & 127;
    float c = 0.f;
    if (tid < 256) {
        int b = b0 + r1;
        c = cfin[b * 128 + u1] + cfin[65536 + b * 128 + u1];
        h_lds[r1][u1] = hfin[b * 128 + u1] + hfin[65536 + b * 128 + u1];
    }
    __syncthreads();

    for (int t = 0; t < T_; ++t) {
        int tok0 = (t == 0) ? 0 : target[(b0 + 0) * T_ + t - 1];
        int tok1 = (t == 0) ? 0 : target[(b0 + 1) * T_ + t - 1];
        float a0 = xt_d[tok0 * 512 + j];
        float a1 = xt_d[tok1 * 512 + j];
        #pragma unroll
        for (int kc = 0; kc < 32; ++kc) {
            const float4 w = w4[kc];
            const float4 h0 = *reinterpret_cast<const float4*>(&h_lds[0][kc * 4]);
            const float4 h1 = *reinterpret_cast<const float4*>(&h_lds[1][kc * 4]);
            a0 = fmaf(h0.x, w.x, a0); a0 = fmaf(h0.y, w.y, a0); a0 = fmaf(h0.z, w.z, a0); a0 = fmaf(h0.w, w.w, a0);
            a1 = fmaf(h1.x, w.x, a1); a1 = fmaf(h1.y, w.y, a1); a1 = fmaf(h1.z, w.z, a1); a1 = fmaf(h1.w, w.w, a1);
        }
        g_lds[0][j] = a0; g_lds[1][j] = a1;
        __syncthreads();
        if (tid < 256) {
            float gi = g_lds[r1][u1], gf = g_lds[r1][u1 + 128];
            float gg = g_lds[r1][u1 + 256], go = g_lds[r1][u1 + 384];
            float ii = sigm(gi), ff = sigm(gf), g_ = tanh_(gg), oo = sigm(go);
            c = ff * c + ii * g_;
            float h = oo * tanh_(c);
            h_lds[r1][u1] = h;
            hdec[((size_t)(b0 + r1) * T_ + t) * 128 + u1] = h;
        }
        __syncthreads();
    }
}

// ---------------- attention + output: 512 threads, no e-LDS, 2 blocks/CU ----------------
__global__ __launch_bounds__(512, 2) void attn_kernel(
    const float* __restrict__ hdec,
    const float* __restrict__ projW, const float* __restrict__ proj_b,
    const float* __restrict__ projWT,
    const float* __restrict__ attn_WT, const float* __restrict__ attn_b,
    const float* __restrict__ out_WT, const float* __restrict__ out_b,
    const ushort_t* __restrict__ hs, float* __restrict__ out)
{
    const int b = blockIdx.x;
    const int tid = threadIdx.x;

    __shared__ __align__(16) float hd[1280];      // hdec[10][128]
    __shared__ __align__(16) float q[2560];       // q (swizzled) -> ctx [0..1280) + comb [1280..)
    __shared__ __align__(16) float sc[2560];      // scores -> aw [10][256]
    __shared__ __align__(16) float part[10240];   // wsum partials [4][10][256]
    __shared__ __align__(16) float wsum[3072];    // [10][256] (+pad rows 10,11)

    const ushort_t* e = hs + (size_t)b * 65536;

    for (int i = tid; i < 1280; i += 512) hd[i] = hdec[(size_t)b * 1280 + i];
    __syncthreads();

    // phase 0: q[t][d]; half 0 -> t 0..4, half 1 -> t 5..9
    {
        const int half = tid >> 8, d = tid & 255;
        float acc[5];
        #pragma unroll
        for (int i = 0; i < 5; ++i) acc[i] = 0.f;
        for (int k = 0; k < 128; ++k) {
            float pw = projW[k * 256 + d];
            #pragma unroll
            for (int i = 0; i < 5; ++i) acc[i] = fmaf(hd[(half * 5 + i) * 128 + k], pw, acc[i]);
        }
        int swd = d ^ ((((uint_t)d >> 5) & 7) << 2);
        #pragma unroll
        for (int i = 0; i < 5; ++i) q[(half * 5 + i) * 256 + swd] = acc[i];
    }
    __syncthreads();

    // phase 1: scores[t][s] = e[s][:] . q[t][:]  (8 waves x 32 s, global stream)
    {
        const int w = tid >> 6, l = tid & 63;
        const int s3 = l >> 3, k8 = l & 7;
        for (int pass = 0; pass < 4; ++pass) {
            int s = w * 32 + pass * 8 + s3;
            const ushort_t* row = e + s * 256 + k8 * 32;
            uint4 e0 = *reinterpret_cast<const uint4*>(row);
            uint4 e1 = *reinterpret_cast<const uint4*>(row + 8);
            uint4 e2 = *reinterpret_cast<const uint4*>(row + 16);
            uint4 e3 = *reinterpret_cast<const uint4*>(row + 24);
            float acc[10];
            #pragma unroll
            for (int t = 0; t < 10; ++t) {
                const float* qb = &q[t * 256];
                float a = 0.f;
                #define QCH(i) (*reinterpret_cast<const float4*>(&qb[(k8 * 32 + (i) * 4) ^ (k8 << 2)]))
                #define DOT4(pa, pb, qv) { float4 q_ = (qv); \
                    a = fmaf(bflo(pa), q_.x, a); a = fmaf(bfhi(pa), q_.y, a); \
                    a = fmaf(bflo(pb), q_.z, a); a = fmaf(bfhi(pb), q_.w, a); }
                DOT4(e0.x, e0.y, QCH(0)); DOT4(e0.z, e0.w, QCH(1));
                DOT4(e1.x, e1.y, QCH(2)); DOT4(e1.z, e1.w, QCH(3));
                DOT4(e2.x, e2.y, QCH(4)); DOT4(e2.z, e2.w, QCH(5));
                DOT4(e3.x, e3.y, QCH(6)); DOT4(e3.z, e3.w, QCH(7));
                #undef QCH
                #undef DOT4
                acc[t] = a;
            }
            #pragma unroll
            for (int t = 0; t < 10; ++t) {
                acc[t] += __shfl_xor(acc[t], 1);
                acc[t] += __shfl_xor(acc[t], 2);
                acc[t] += __shfl_xor(acc[t], 4);
            }
            if (k8 == 0) {
                #pragma unroll
                for (int t = 0; t < 10; ++t) sc[t * 256 + s] = acc[t];
            }
        }
    }
    __syncthreads();

    // phase 2: softmax (wave per t; waves 0,1 take two)
    {
        const int w = tid >> 6, l = tid & 63;
        for (int t = w; t < 10; t += 8) {
            float4 sv = *reinterpret_cast<const float4*>(&sc[t * 256 + l * 4]);
            float m = fmaxf(fmaxf(sv.x, sv.y), fmaxf(sv.z, sv.w));
            #pragma unroll
            for (int o = 1; o < 64; o <<= 1) m = fmaxf(m, __shfl_xor(m, o));
            float e0 = fast_exp2((sv.x - m) * 1.4426950408889634f);
            float e1 = fast_exp2((sv.y - m) * 1.4426950408889634f);
            float e2 = fast_exp2((sv.z - m) * 1.4426950408889634f);
            float e3 = fast_exp2((sv.w - m) * 1.4426950408889634f);
            float ssum = e0 + e1 + e2 + e3;
            #pragma unroll
            for (int o = 1; o < 64; o <<= 1) ssum += __shfl_xor(ssum, o);
            float inv = fast_rcp(ssum);
            *reinterpret_cast<float4*>(&sc[t * 256 + l * 4]) =
                make_float4(e0 * inv, e1 * inv, e2 * inv, e3 * inv);
        }
    }
    __syncthreads();

    // phase 3: wsum partials -- wave-pair shares s-chunk of 64, splits t 5/5
    {
        const int w = tid >> 6, l = tid & 63;
        const int chunk = w >> 1, tH = (w & 1) * 5;
        float ax[5], ay[5], az[5], aw2[5];
        #pragma unroll
        for (int i = 0; i < 5; ++i) { ax[i] = 0.f; ay[i] = 0.f; az[i] = 0.f; aw2[i] = 0.f; }
        const ushort_t* col = e + l * 4;
        for (int s = chunk * 64; s < chunk * 64 + 64; ++s) {
            uint2 uu = *reinterpret_cast<const uint2*>(col + (size_t)s * 256);
            float v0 = bflo(uu.x), v1 = bfhi(uu.x), v2 = bflo(uu.y), v3 = bfhi(uu.y);
            #pragma unroll
            for (int i = 0; i < 5; ++i) {
                float awv = sc[(tH + i) * 256 + s];
                ax[i] = fmaf(v0, awv, ax[i]); ay[i] = fmaf(v1, awv, ay[i]);
                az[i] = fmaf(v2, awv, az[i]); aw2[i] = fmaf(v3, awv, aw2[i]);
            }
        }
        #pragma unroll
        for (int i = 0; i < 5; ++i)
            *reinterpret_cast<float4*>(&part[(chunk * 10 + tH + i) * 256 + l * 4]) =
                make_float4(ax[i], ay[i], az[i], aw2[i]);
    }
    __syncthreads();

    // phase 4: reduce partials
    for (int i = tid; i < 2560; i += 512)
        wsum[i] = part[i] + part[2560 + i] + part[5120 + i] + part[7680 + i];
    for (int i = tid; i < 512; i += 512) { wsum[2560 + i] = 0.f; }   // pad rows 10,11
    __syncthreads();

    // phase 5: ctx[t][u] -> q[0..1280); th groups t {0-2,3-5,6-7,8-9}
    {
        const int u = tid & 127, th = tid >> 7;
        const int st = (th < 2) ? th * 3 : 6 + (th - 2) * 2;
        const int cn = (th < 2) ? 3 : 2;
        float acc[3];
        #pragma unroll
        for (int i = 0; i < 3; ++i) acc[i] = proj_b[u];
        for (int k = 0; k < 256; ++k) {
            float pw = projWT[k * 128 + u];
            #pragma unroll
            for (int i = 0; i < 3; ++i) acc[i] = fmaf(pw, wsum[(st + i) * 256 + k], acc[i]);
        }
        #pragma unroll
        for (int i = 0; i < 3; ++i)
            if (i < cn) q[(st + i) * 128 + u] = acc[i];
    }
    __syncthreads();

    // phase 6: comb[t][u] = tanh(...) -> q[1280..2560)
    {
        const int u = tid & 127, th = tid >> 7;
        const int st = (th < 2) ? th * 3 : 6 + (th - 2) * 2;
        const int cn = (th < 2) ? 3 : 2;
        float acc[3];
        #pragma unroll
        for (int i = 0; i < 3; ++i) acc[i] = attn_b[u];
        for (int k = 0; k < 128; ++k) {
            float a1 = attn_WT[k * 128 + u];
            #pragma unroll
            for (int i = 0; i < 3; ++i) {
                int tt = (st + i < 10) ? (st + i) : 9;
                acc[i] = fmaf(a1, hd[tt * 128 + k], acc[i]);
            }
        }
        for (int k = 0; k < 128; ++k) {
            float a2 = attn_WT[(128 + k) * 128 + u];
            #pragma unroll
            for (int i = 0; i < 3; ++i) {
                int tt = (st + i < 10) ? (st + i) : 9;
                acc[i] = fmaf(a2, q[tt * 128 + k], acc[i]);
            }
        }
        #pragma unroll
        for (int i = 0; i < 3; ++i)
            if (i < cn) q[1280 + (st + i) * 128 + u] = tanh_(acc[i]);
    }
    __syncthreads();

    // phase 7: logits
    for (int o = tid; o < 280; o += 512) {
        int t = o / 28, v = o - t * 28;
        float acc = out_b[v];
        #pragma unroll 4
        for (int k = 0; k < 128; ++k)
            acc = fmaf(out_WT[k * 28 + v], q[1280 + t * 128 + k], acc);
        out[(size_t)b * 280 + o] = acc;
    }
}

extern "C" void kernel_launch(void* const* d_in, const int* in_sizes, int n_in,
                              void* d_out, int out_size, void* d_ws, size_t ws_size,
                              hipStream_t stream) {
    const int* src      = (const int*)d_in[0];
    const int* target   = (const int*)d_in[1];
    const float* embed  = (const float*)d_in[2];
    const float* Wih_f  = (const float*)d_in[3];
    const float* Whh_f  = (const float*)d_in[4];
    const float* b_f    = (const float*)d_in[5];
    const float* Wih_b  = (const float*)d_in[6];
    const float* Whh_b  = (const float*)d_in[7];
    const float* b_b    = (const float*)d_in[8];
    const float* Wih_d  = (const float*)d_in[9];
    const float* Whh_d  = (const float*)d_in[10];
    const float* b_d    = (const float*)d_in[11];
    const float* proj_W = (const float*)d_in[12];
    const float* proj_b = (const float*)d_in[13];
    const float* attn_W = (const float*)d_in[14];
    const float* attn_b = (const float*)d_in[15];
    const float* out_W  = (const float*)d_in[16];
    const float* out_b  = (const float*)d_in[17];

    float* ws = (float*)d_ws;
    ushort_t* hs = (ushort_t*)((char*)d_ws + HS_BYTE_OFF);
    float* out = (float*)d_out;

    prep_kernel<<<(PREP_N + 255) / 256, 256, 0, stream>>>(
        embed, Wih_f, b_f, Wih_b, b_b, Wih_d, b_d,
        Whh_f, Whh_b, Whh_d, attn_W, out_W, proj_W, ws);

    enc_kernel<<<256, 512, 0, stream>>>(
        src, ws + XTG, (const ushort_t*)(ws + WPK),
        ws + HFIN, ws + CFIN, hs);

    dec_lstm_kernel<<<256, 512, 0, stream>>>(
        target, ws + XTD, ws + WTD, ws + HFIN, ws + CFIN, ws + HDEC);

    attn_kernel<<<512, 512, 0, stream>>>(
        ws + HDEC, proj_W, proj_b, ws + PWT, ws + AWT, attn_b,
        ws + OWT, out_b, hs, out);
}

// Round 15
// 280.624 us; speedup vs baseline: 1.2870x; 1.2870x over previous
//
#include <hip/hip_runtime.h>
#include <hip/hip_bf16.h>
#include <stdint.h>

typedef unsigned short ushort_t;
typedef unsigned int uint_t;
typedef __attribute__((ext_vector_type(8))) short bfrag;   // 8 bf16 = 4 VGPR
typedef __attribute__((ext_vector_type(4))) float f32x4;

#define B_ 512
#define S_ 256
#define T_ 10
#define V_ 28
#define H_ 128

// ---- workspace layout (float element offsets) ----
#define XTD 0         // dec xg table [28][512]
#define XTG 14336     // enc xg gate-interleaved [2][28][128][4]
#define WTD 43008     // dec WhhT [128][512]
#define AWT 108544    // attn_WT [256][128]
#define OWT 141312    // out_WT [128][28]
#define PWT 144896    // projWT [256][128]
#define WPK 177664    // enc W_hi bf16 frag pack, 131072 ushort (K=128)
#define HFIN 308736
#define CFIN 439808
#define HDEC 570880
#define HS_BYTE_OFF (1226240ull * 4ull)
#define PREP_N 308736

__device__ __forceinline__ float fast_exp2(float x) { return __builtin_amdgcn_exp2f(x); }
__device__ __forceinline__ float fast_rcp(float x)  { return __builtin_amdgcn_rcpf(x); }
__device__ __forceinline__ float sigm(float x) {
    return fast_rcp(1.f + fast_exp2(-1.4426950408889634f * x));
}
__device__ __forceinline__ float tanh_(float x) {
    return 1.f - 2.f * fast_rcp(1.f + fast_exp2(2.8853900817779268f * x));
}
__device__ __forceinline__ ushort_t f2bf(float x) {
    uint_t u = __float_as_uint(x);
    return (ushort_t)((u + 0x7FFFu + ((u >> 16) & 1u)) >> 16);  // RNE
}
__device__ __forceinline__ float bflo(uint_t u) { return __uint_as_float(u << 16); }
__device__ __forceinline__ float bfhi(uint_t u) { return __uint_as_float(u & 0xFFFF0000u); }

// LDS-only barrier: drain LDS ops, sync, fence scheduler (rule #18).
__device__ __forceinline__ void lds_barrier() {
    asm volatile("s_waitcnt lgkmcnt(0)" ::: "memory");
    __builtin_amdgcn_s_barrier();
    __builtin_amdgcn_sched_barrier(0);
}

// ---------------- prep (unchanged) ----------------
__global__ __launch_bounds__(256) void prep_kernel(
    const float* __restrict__ embed,
    const float* __restrict__ Wih_f, const float* __restrict__ b_f,
    const float* __restrict__ Wih_b, const float* __restrict__ b_b,
    const float* __restrict__ Wih_d, const float* __restrict__ b_d,
    const float* __restrict__ Whh_f, const float* __restrict__ Whh_b,
    const float* __restrict__ Whh_d,
    const float* __restrict__ attn_W, const float* __restrict__ out_W,
    const float* __restrict__ proj_W,
    float* __restrict__ ws)
{
    int i = blockIdx.x * 256 + threadIdx.x;
    if (i < XTG) {                         // dec xg table: [v][j]
        int v = i >> 9, jj = i & 511;
        float acc = b_d[jj];
        #pragma unroll
        for (int e = 0; e < 32; ++e) acc = fmaf(embed[v * 32 + e], Wih_d[jj * 32 + e], acc);
        ws[XTD + i] = acc;
    } else if (i < WTD) {                  // enc xg gate-interleaved: [d][v][u][g]
        int r = i - XTG; int d = r / 14336; int rem = r % 14336;
        int v = rem >> 9, q = rem & 511;
        int uu = q >> 2, g = q & 3;
        int jj = g * 128 + uu;
        const float* Wih = d ? Wih_b : Wih_f;
        const float* bb  = d ? b_b   : b_f;
        float acc = bb[jj];
        #pragma unroll
        for (int e = 0; e < 32; ++e) acc = fmaf(embed[v * 32 + e], Wih[jj * 32 + e], acc);
        ws[XTG + r] = acc;
    } else if (i < AWT) {                  // dec WhhT[k][j]
        int r = i - WTD; int k = r >> 9, jj = r & 511;
        ws[WTD + r] = Whh_d[jj * 128 + k];
    } else if (i < OWT) {                  // attn_WT[k][u]
        int r = i - AWT; int k = r >> 7, uu = r & 127;
        ws[i] = attn_W[uu * 256 + k];
    } else if (i < PWT) {                  // out_WT[k][v]
        int r = i - OWT; int k = r / 28, v = r % 28;
        ws[i] = out_W[v * 128 + k];
    } else if (i < WPK) {                  // projWT[k][u]
        int r = i - PWT; int k = r >> 7, uu = r & 127;
        ws[i] = proj_W[uu * 256 + k];
    } else if (i < PREP_N) {               // enc W_hi frag pack, K=128 (pure bf16 hi)
        int i2 = (i - WPK) * 2;            // 2 ushorts per thread
        #pragma unroll
        for (int p = 0; p < 2; ++p, ++i2) {
            int e  = i2 & 7;
            int ll = (i2 >> 3) & 63;
            int kt = (i2 >> 9) & 3;
            int ni = (i2 >> 11) & 3;
            int wv = (i2 >> 13) & 7;
            int d  = (i2 >> 16) & 1;
            int jj = (ni * 8 + wv) * 16 + (ll & 15);   // gate column (N)
            int kp = kt * 32 + ((ll >> 4) << 3) + e;   // K index 0..127
            const float* Whh = d ? Whh_b : Whh_f;
            ((ushort_t*)(ws + WPK))[i2] = f2bf(Whh[jj * 128 + kp]);
        }
    }
}

// ---------------- encoder (unchanged from round 14) ----------------
__global__ __launch_bounds__(512, 2) void enc_kernel(
    const int* __restrict__ src,
    const float* __restrict__ xtg_base,     // ws+XTG
    const ushort_t* __restrict__ wpk,       // ws+WPK
    float* __restrict__ hfin, float* __restrict__ cfin,
    ushort_t* __restrict__ hs)
{
    const int bx = blockIdx.x;
    const int dir = bx >> 7;
    const int b0 = (bx & 127) << 2;
    const int tid = threadIdx.x;
    const int w = tid >> 6, l = tid & 63;
    const int lg = l >> 4, col = l & 15;
    const int u = (w << 4) + col;
    const int row = lg;

    __shared__ __align__(16) ushort_t hb[2][4][144];
    __shared__ __align__(16) int tokl[256][4];

    for (int i = tid; i < 1024; i += 512)
        tokl[i >> 2][i & 3] = src[(b0 + (i & 3)) * S_ + (i >> 2)];
    for (int i = tid; i < 576; i += 512) ((uint_t*)hb)[i] = 0u;

    const float* xtg = xtg_base + dir * 14336;

    bfrag bf[4][4];
    {
        const ushort_t* wb = wpk + (((size_t)dir * 8 + w) << 13) + l * 8;
        #pragma unroll
        for (int ni = 0; ni < 4; ++ni)
            #pragma unroll
            for (int kt = 0; kt < 4; ++kt)
                bf[ni][kt] = *reinterpret_cast<const bfrag*>(wb + ((ni * 4 + kt) << 9));
    }
    __syncthreads();

    float c_reg = 0.f, h_reg = 0.f;

    f32x4 xg_cur, xg_next;
    {
        int p0 = dir ? (S_ - 1) : 0;
        xg_cur = *reinterpret_cast<const f32x4*>(xtg + ((size_t)tokl[p0][row] << 9) + (u << 2));
    }

    const bfrag zf = {0, 0, 0, 0, 0, 0, 0, 0};
    bfrag af0 = zf, af1 = zf, af2 = zf, af3 = zf;
    const bool ard = ((col & 3) == 0);
    const int ar = col >> 2;
    const int swz = ar << 3;
    const f32x4 zacc = {0.f, 0.f, 0.f, 0.f};

    ushort_t* hs_ptr = hs + ((size_t)(b0 + row) * S_ + (dir ? (S_ - 1) : 0)) * 256
                          + dir * 128 + u;
    const int hs_step = dir ? -256 : 256;

    for (int t = 0; t < S_; ++t) {
        const int cb = t & 1, nb = cb ^ 1;

        if (t + 1 < S_) {
            int pn = dir ? (S_ - 2 - t) : (t + 1);
            xg_next = *reinterpret_cast<const f32x4*>(xtg + ((size_t)tokl[pn][row] << 9) + (u << 2));
        }

        if (ard) {
            const ushort_t* hp = &hb[cb][ar][0];
            af0 = *reinterpret_cast<const bfrag*>(hp + ((  0 + (lg << 3)) ^ swz));
            af1 = *reinterpret_cast<const bfrag*>(hp + (( 32 + (lg << 3)) ^ swz));
            af2 = *reinterpret_cast<const bfrag*>(hp + (( 64 + (lg << 3)) ^ swz));
            af3 = *reinterpret_cast<const bfrag*>(hp + (( 96 + (lg << 3)) ^ swz));
        }

        f32x4 a0 = __builtin_amdgcn_mfma_f32_16x16x32_bf16(af0, bf[0][0], zacc, 0, 0, 0);
        f32x4 a1 = __builtin_amdgcn_mfma_f32_16x16x32_bf16(af0, bf[1][0], zacc, 0, 0, 0);
        f32x4 a2 = __builtin_amdgcn_mfma_f32_16x16x32_bf16(af0, bf[2][0], zacc, 0, 0, 0);
        f32x4 a3 = __builtin_amdgcn_mfma_f32_16x16x32_bf16(af0, bf[3][0], zacc, 0, 0, 0);
        #define KT1(AF, kt) { \
            a0 = __builtin_amdgcn_mfma_f32_16x16x32_bf16(AF, bf[0][kt], a0, 0, 0, 0); \
            a1 = __builtin_amdgcn_mfma_f32_16x16x32_bf16(AF, bf[1][kt], a1, 0, 0, 0); \
            a2 = __builtin_amdgcn_mfma_f32_16x16x32_bf16(AF, bf[2][kt], a2, 0, 0, 0); \
            a3 = __builtin_amdgcn_mfma_f32_16x16x32_bf16(AF, bf[3][kt], a3, 0, 0, 0); \
        }
        KT1(af1, 1) KT1(af2, 2) KT1(af3, 3)
        #undef KT1

        {
            float gi = a0[0] + xg_cur[0], gf = a1[0] + xg_cur[1];
            float gg = a2[0] + xg_cur[2], go = a3[0] + xg_cur[3];
            float ii = sigm(gi), ff = sigm(gf), gG = tanh_(gg), oo = sigm(go);
            c_reg = ff * c_reg + ii * gG;
            float h = oo * tanh_(c_reg);
            h_reg = h;
            ushort_t hi = f2bf(h);
            hb[nb][row][u ^ (row << 3)] = hi;
            *hs_ptr = hi;
            hs_ptr += hs_step;
        }
        xg_cur = xg_next;
        lds_barrier();
    }

    hfin[dir * 65536 + (b0 + row) * 128 + u] = h_reg;
    cfin[dir * 65536 + (b0 + row) * 128 + u] = c_reg;
}

// ---------------- decoder LSTM only (unchanged) ----------------
__global__ __launch_bounds__(512, 1) void dec_lstm_kernel(
    const int* __restrict__ target,
    const float* __restrict__ xt_d,
    const float* __restrict__ WhhT_d,
    const float* __restrict__ hfin, const float* __restrict__ cfin,
    float* __restrict__ hdec)
{
    const int b0 = blockIdx.x * 2;
    const int tid = threadIdx.x;
    const int j = tid;

    __shared__ __align__(16) float h_lds[2][128];
    __shared__ __align__(16) float g_lds[2][512];

    float4 w4[32];
    #pragma unroll
    for (int kc = 0; kc < 32; ++kc) {
        w4[kc].x = WhhT_d[(kc * 4 + 0) * 512 + j];
        w4[kc].y = WhhT_d[(kc * 4 + 1) * 512 + j];
        w4[kc].z = WhhT_d[(kc * 4 + 2) * 512 + j];
        w4[kc].w = WhhT_d[(kc * 4 + 3) * 512 + j];
    }
    const int r1 = tid >> 7, u1 = tid & 127;
    float c = 0.f;
    if (tid < 256) {
        int b = b0 + r1;
        c = cfin[b * 128 + u1] + cfin[65536 + b * 128 + u1];
        h_lds[r1][u1] = hfin[b * 128 + u1] + hfin[65536 + b * 128 + u1];
    }
    __syncthreads();

    for (int t = 0; t < T_; ++t) {
        int tok0 = (t == 0) ? 0 : target[(b0 + 0) * T_ + t - 1];
        int tok1 = (t == 0) ? 0 : target[(b0 + 1) * T_ + t - 1];
        float a0 = xt_d[tok0 * 512 + j];
        float a1 = xt_d[tok1 * 512 + j];
        #pragma unroll
        for (int kc = 0; kc < 32; ++kc) {
            const float4 w = w4[kc];
            const float4 h0 = *reinterpret_cast<const float4*>(&h_lds[0][kc * 4]);
            const float4 h1 = *reinterpret_cast<const float4*>(&h_lds[1][kc * 4]);
            a0 = fmaf(h0.x, w.x, a0); a0 = fmaf(h0.y, w.y, a0); a0 = fmaf(h0.z, w.z, a0); a0 = fmaf(h0.w, w.w, a0);
            a1 = fmaf(h1.x, w.x, a1); a1 = fmaf(h1.y, w.y, a1); a1 = fmaf(h1.z, w.z, a1); a1 = fmaf(h1.w, w.w, a1);
        }
        g_lds[0][j] = a0; g_lds[1][j] = a1;
        __syncthreads();
        if (tid < 256) {
            float gi = g_lds[r1][u1], gf = g_lds[r1][u1 + 128];
            float gg = g_lds[r1][u1 + 256], go = g_lds[r1][u1 + 384];
            float ii = sigm(gi), ff = sigm(gf), g_ = tanh_(gg), oo = sigm(go);
            c = ff * c + ii * g_;
            float h = oo * tanh_(c);
            h_lds[r1][u1] = h;
            hdec[((size_t)(b0 + r1) * T_ + t) * 128 + u1] = h;
        }
        __syncthreads();
    }
}

// ---------------- attention: 512 threads + full e-LDS staging (R13 mem plan, R14 split) ----------------
#define ESW(unit, row) ((((unit) ^ ((row) & 31))) << 3)   // ushort offset within row
__global__ __launch_bounds__(512, 1) void attn_kernel(
    const float* __restrict__ hdec,
    const float* __restrict__ projW, const float* __restrict__ proj_b,
    const float* __restrict__ projWT,
    const float* __restrict__ attn_WT, const float* __restrict__ attn_b,
    const float* __restrict__ out_WT, const float* __restrict__ out_b,
    const ushort_t* __restrict__ hs, float* __restrict__ out)
{
    const int b = blockIdx.x;
    const int tid = threadIdx.x;

    __shared__ __align__(16) char smem[156672];
    ushort_t* e_lds = (ushort_t*)smem;                    // [256][256] swizzled = 131072 B
    float* hd   = (float*)(smem + 131072);                // [10][128]  = 5120 B
    float* q    = (float*)(smem + 136192);                // [2560]     = 10240 B
    float* sc   = (float*)(smem + 146432);                // [2560]     = 10240 B
    float* part = (float*)smem;                           // alias after phase 3: [4][10][256]
    float* wsum = (float*)(smem + 40960);                 // alias: [12][256] (rows 10,11 pad)

    const ushort_t* e = hs + (size_t)b * 65536;

    // stage e -> LDS (swizzled 16B units, 16 per thread)
    #pragma unroll 4
    for (int i = 0; i < 16; ++i) {
        int idx = i * 512 + tid;           // 16B-unit index 0..8191
        int row = idx >> 5, c = idx & 31;
        uint4 v = *reinterpret_cast<const uint4*>(e + idx * 8);
        *reinterpret_cast<uint4*>(e_lds + row * 256 + ESW(c, row)) = v;
    }
    for (int i = tid; i < 1280; i += 512) hd[i] = hdec[(size_t)b * 1280 + i];
    __syncthreads();

    // phase 0: q[t][d]; half 0 -> t 0..4, half 1 -> t 5..9 (swizzle-stored)
    {
        const int half = tid >> 8, d = tid & 255;
        float acc[5];
        #pragma unroll
        for (int i = 0; i < 5; ++i) acc[i] = 0.f;
        for (int k = 0; k < 128; ++k) {
            float pw = projW[k * 256 + d];
            #pragma unroll
            for (int i = 0; i < 5; ++i) acc[i] = fmaf(hd[(half * 5 + i) * 128 + k], pw, acc[i]);
        }
        int swd = d ^ ((((uint_t)d >> 5) & 7) << 2);
        #pragma unroll
        for (int i = 0; i < 5; ++i) q[(half * 5 + i) * 256 + swd] = acc[i];
    }
    __syncthreads();

    // phase 1: scores[t][s] = e[s][:] . q[t][:]  -- LDS reads, 8 waves x 32 s
    {
        const int w = tid >> 6, l = tid & 63;
        const int s3 = l >> 3, k8 = l & 7;
        for (int pass = 0; pass < 4; ++pass) {
            int s = w * 32 + pass * 8 + s3;
            const ushort_t* lrow = e_lds + s * 256;
            uint4 e0 = *reinterpret_cast<const uint4*>(lrow + ESW((k8 << 2) + 0, s));
            uint4 e1 = *reinterpret_cast<const uint4*>(lrow + ESW((k8 << 2) + 1, s));
            uint4 e2 = *reinterpret_cast<const uint4*>(lrow + ESW((k8 << 2) + 2, s));
            uint4 e3 = *reinterpret_cast<const uint4*>(lrow + ESW((k8 << 2) + 3, s));
            float acc[10];
            #pragma unroll
            for (int t = 0; t < 10; ++t) {
                const float* qb = &q[t * 256];
                float a = 0.f;
                #define QCH(i) (*reinterpret_cast<const float4*>(&qb[(k8 * 32 + (i) * 4) ^ (k8 << 2)]))
                #define DOT4(pa, pb, qv) { float4 q_ = (qv); \
                    a = fmaf(bflo(pa), q_.x, a); a = fmaf(bfhi(pa), q_.y, a); \
                    a = fmaf(bflo(pb), q_.z, a); a = fmaf(bfhi(pb), q_.w, a); }
                DOT4(e0.x, e0.y, QCH(0)); DOT4(e0.z, e0.w, QCH(1));
                DOT4(e1.x, e1.y, QCH(2)); DOT4(e1.z, e1.w, QCH(3));
                DOT4(e2.x, e2.y, QCH(4)); DOT4(e2.z, e2.w, QCH(5));
                DOT4(e3.x, e3.y, QCH(6)); DOT4(e3.z, e3.w, QCH(7));
                #undef QCH
                #undef DOT4
                acc[t] = a;
            }
            #pragma unroll
            for (int t = 0; t < 10; ++t) {
                acc[t] += __shfl_xor(acc[t], 1);
                acc[t] += __shfl_xor(acc[t], 2);
                acc[t] += __shfl_xor(acc[t], 4);
            }
            if (k8 == 0) {
                #pragma unroll
                for (int t = 0; t < 10; ++t) sc[t * 256 + s] = acc[t];
            }
        }
    }
    __syncthreads();

    // phase 2: softmax (wave per t)
    {
        const int w = tid >> 6, l = tid & 63;
        for (int t = w; t < 10; t += 8) {
            float4 sv = *reinterpret_cast<const float4*>(&sc[t * 256 + l * 4]);
            float m = fmaxf(fmaxf(sv.x, sv.y), fmaxf(sv.z, sv.w));
            #pragma unroll
            for (int o = 1; o < 64; o <<= 1) m = fmaxf(m, __shfl_xor(m, o));
            float e0 = fast_exp2((sv.x - m) * 1.4426950408889634f);
            float e1 = fast_exp2((sv.y - m) * 1.4426950408889634f);
            float e2 = fast_exp2((sv.z - m) * 1.4426950408889634f);
            float e3 = fast_exp2((sv.w - m) * 1.4426950408889634f);
            float ssum = e0 + e1 + e2 + e3;
            #pragma unroll
            for (int o = 1; o < 64; o <<= 1) ssum += __shfl_xor(ssum, o);
            float inv = fast_rcp(ssum);
            *reinterpret_cast<float4*>(&sc[t * 256 + l * 4]) =
                make_float4(e0 * inv, e1 * inv, e2 * inv, e3 * inv);
        }
    }
    __syncthreads();

    // phase 3: wsum partials -- e from LDS; wave-pair shares s-chunk, splits t 5/5
    {
        const int w = tid >> 6, l = tid & 63;
        const int chunk = w >> 1, tH = (w & 1) * 5;
        const int unit = l >> 1, half = (l & 1) << 2;
        float ax[5], ay[5], az[5], aw2[5];
        #pragma unroll
        for (int i = 0; i < 5; ++i) { ax[i] = 0.f; ay[i] = 0.f; az[i] = 0.f; aw2[i] = 0.f; }
        for (int s = chunk * 64; s < chunk * 64 + 64; ++s) {
            uint2 uu = *reinterpret_cast<const uint2*>(e_lds + s * 256 + ESW(unit, s) + half);
            float v0 = bflo(uu.x), v1 = bfhi(uu.x), v2 = bflo(uu.y), v3 = bfhi(uu.y);
            #pragma unroll
            for (int i = 0; i < 5; ++i) {
                float awv = sc[(tH + i) * 256 + s];
                ax[i] = fmaf(v0, awv, ax[i]); ay[i] = fmaf(v1, awv, ay[i]);
                az[i] = fmaf(v2, awv, az[i]); aw2[i] = fmaf(v3, awv, aw2[i]);
            }
        }
        __syncthreads();   // all e_lds reads complete before aliasing writes
        #pragma unroll
        for (int i = 0; i < 5; ++i)
            *reinterpret_cast<float4*>(&part[(chunk * 10 + tH + i) * 256 + l * 4]) =
                make_float4(ax[i], ay[i], az[i], aw2[i]);
    }
    __syncthreads();

    // phase 4: reduce partials (+zero pad rows 10,11 of wsum)
    for (int i = tid; i < 2560; i += 512)
        wsum[i] = part[i] + part[2560 + i] + part[5120 + i] + part[7680 + i];
    if (tid < 512) wsum[2560 + tid] = 0.f;
    __syncthreads();

    // phase 5: ctx[t][u] -> q[0..1280); th groups t {0-2,3-5,6-7,8-9}
    {
        const int u = tid & 127, th = tid >> 7;
        const int st = (th < 2) ? th * 3 : 6 + (th - 2) * 2;
        const int cn = (th < 2) ? 3 : 2;
        float acc[3];
        #pragma unroll
        for (int i = 0; i < 3; ++i) acc[i] = proj_b[u];
        for (int k = 0; k < 256; ++k) {
            float pw = projWT[k * 128 + u];
            #pragma unroll
            for (int i = 0; i < 3; ++i) acc[i] = fmaf(pw, wsum[(st + i) * 256 + k], acc[i]);
        }
        #pragma unroll
        for (int i = 0; i < 3; ++i)
            if (i < cn) q[(st + i) * 128 + u] = acc[i];
    }
    __syncthreads();

    // phase 6: comb[t][u] = tanh(...) -> q[1280..2560)
    {
        const int u = tid & 127, th = tid >> 7;
        const int st = (th < 2) ? th * 3 : 6 + (th - 2) * 2;
        const int cn = (th < 2) ? 3 : 2;
        float acc[3];
        #pragma unroll
        for (int i = 0; i < 3; ++i) acc[i] = attn_b[u];
        for (int k = 0; k < 128; ++k) {
            float a1 = attn_WT[k * 128 + u];
            #pragma unroll
            for (int i = 0; i < 3; ++i) {
                int tt = (st + i < 10) ? (st + i) : 9;
                acc[i] = fmaf(a1, hd[tt * 128 + k], acc[i]);
            }
        }
        for (int k = 0; k < 128; ++k) {
            float a2 = attn_WT[(128 + k) * 128 + u];
            #pragma unroll
            for (int i = 0; i < 3; ++i) {
                int tt = (st + i < 10) ? (st + i) : 9;
                acc[i] = fmaf(a2, q[tt * 128 + k], acc[i]);
            }
        }
        #pragma unroll
        for (int i = 0; i < 3; ++i)
            if (i < cn) q[1280 + (st + i) * 128 + u] = tanh_(acc[i]);
    }
    __syncthreads();

    // phase 7: logits
    for (int o = tid; o < 280; o += 512) {
        int t = o / 28, v = o - t * 28;
        float acc = out_b[v];
        #pragma unroll 4
        for (int k = 0; k < 128; ++k)
            acc = fmaf(out_WT[k * 28 + v], q[1280 + t * 128 + k], acc);
        out[(size_t)b * 280 + o] = acc;
    }
}

extern "C" void kernel_launch(void* const* d_in, const int* in_sizes, int n_in,
                              void* d_out, int out_size, void* d_ws, size_t ws_size,
                              hipStream_t stream) {
    const int* src      = (const int*)d_in[0];
    const int* target   = (const int*)d_in[1];
    const float* embed  = (const float*)d_in[2];
    const float* Wih_f  = (const float*)d_in[3];
    const float* Whh_f  = (const float*)d_in[4];
    const float* b_f    = (const float*)d_in[5];
    const float* Wih_b  = (const float*)d_in[6];
    const float* Whh_b  = (const float*)d_in[7];
    const float* b_b    = (const float*)d_in[8];
    const float* Wih_d  = (const float*)d_in[9];
    const float* Whh_d  = (const float*)d_in[10];
    const float* b_d    = (const float*)d_in[11];
    const float* proj_W = (const float*)d_in[12];
    const float* proj_b = (const float*)d_in[13];
    const float* attn_W = (const float*)d_in[14];
    const float* attn_b = (const float*)d_in[15];
    const float* out_W  = (const float*)d_in[16];
    const float* out_b  = (const float*)d_in[17];

    float* ws = (float*)d_ws;
    ushort_t* hs = (ushort_t*)((char*)d_ws + HS_BYTE_OFF);
    float* out = (float*)d_out;

    prep_kernel<<<(PREP_N + 255) / 256, 256, 0, stream>>>(
        embed, Wih_f, b_f, Wih_b, b_b, Wih_d, b_d,
        Whh_f, Whh_b, Whh_d, attn_W, out_W, proj_W, ws);

    enc_kernel<<<256, 512, 0, stream>>>(
        src, ws + XTG, (const ushort_t*)(ws + WPK),
        ws + HFIN, ws + CFIN, hs);

    dec_lstm_kernel<<<256, 512, 0, stream>>>(
        target, ws + XTD, ws + WTD, ws + HFIN, ws + CFIN, ws + HDEC);

    attn_kernel<<<512, 512, 0, stream>>>(
        ws + HDEC, proj_W, proj_b, ws + PWT, ws + AWT, attn_b,
        ws + OWT, out_b, hs, out);
}

// Round 16
// 264.595 us; speedup vs baseline: 1.3649x; 1.0606x over previous
//
#include <hip/hip_runtime.h>
#include <hip/hip_bf16.h>
#include <stdint.h>

typedef unsigned short ushort_t;
typedef unsigned int uint_t;
typedef __attribute__((ext_vector_type(8))) short bfrag;   // 8 bf16 = 4 VGPR
typedef __attribute__((ext_vector_type(4))) float f32x4;

#define B_ 512
#define S_ 256
#define T_ 10
#define V_ 28
#define H_ 128

// ---- workspace layout (float element offsets) ----
#define XTD 0         // dec xg gate-interleaved [28][128][4]
#define XTG 14336     // enc xg gate-interleaved [2][28][128][4]
#define WTD 43008     // (dead; kept for prep branch boundaries)
#define AWT 108544    // attn_WT [256][128]
#define OWT 141312    // out_WT [128][28]
#define PWT 144896    // projWT [256][128]
#define WPK 177664    // frag packs: enc f,b = ushort[0..131072), dec = [131072..196608)
#define HFIN 308736
#define CFIN 439808
#define HDEC 570880
#define HS_BYTE_OFF (1226240ull * 4ull)
#define PREP_N 308736

__device__ __forceinline__ float fast_exp2(float x) { return __builtin_amdgcn_exp2f(x); }
__device__ __forceinline__ float fast_rcp(float x)  { return __builtin_amdgcn_rcpf(x); }
__device__ __forceinline__ float sigm(float x) {
    return fast_rcp(1.f + fast_exp2(-1.4426950408889634f * x));
}
__device__ __forceinline__ float tanh_(float x) {
    return 1.f - 2.f * fast_rcp(1.f + fast_exp2(2.8853900817779268f * x));
}
__device__ __forceinline__ ushort_t f2bf(float x) {
    uint_t u = __float_as_uint(x);
    return (ushort_t)((u + 0x7FFFu + ((u >> 16) & 1u)) >> 16);  // RNE
}
__device__ __forceinline__ float bflo(uint_t u) { return __uint_as_float(u << 16); }
__device__ __forceinline__ float bfhi(uint_t u) { return __uint_as_float(u & 0xFFFF0000u); }

// LDS-only barrier: drain LDS ops, sync, fence scheduler (rule #18).
__device__ __forceinline__ void lds_barrier() {
    asm volatile("s_waitcnt lgkmcnt(0)" ::: "memory");
    __builtin_amdgcn_s_barrier();
    __builtin_amdgcn_sched_barrier(0);
}

// ---------------- prep ----------------
__global__ __launch_bounds__(256) void prep_kernel(
    const float* __restrict__ embed,
    const float* __restrict__ Wih_f, const float* __restrict__ b_f,
    const float* __restrict__ Wih_b, const float* __restrict__ b_b,
    const float* __restrict__ Wih_d, const float* __restrict__ b_d,
    const float* __restrict__ Whh_f, const float* __restrict__ Whh_b,
    const float* __restrict__ Whh_d,
    const float* __restrict__ attn_W, const float* __restrict__ out_W,
    const float* __restrict__ proj_W,
    float* __restrict__ ws)
{
    int i = blockIdx.x * 256 + threadIdx.x;
    if (i < XTG) {                         // dec xg gate-interleaved [v][u][g]
        int v = i >> 9, q = i & 511;
        int uu = q >> 2, g = q & 3;
        int jj = g * 128 + uu;
        float acc = b_d[jj];
        #pragma unroll
        for (int e = 0; e < 32; ++e) acc = fmaf(embed[v * 32 + e], Wih_d[jj * 32 + e], acc);
        ws[XTD + i] = acc;
    } else if (i < WTD) {                  // enc xg gate-interleaved: [d][v][u][g]
        int r = i - XTG; int d = r / 14336; int rem = r % 14336;
        int v = rem >> 9, q = rem & 511;
        int uu = q >> 2, g = q & 3;
        int jj = g * 128 + uu;
        const float* Wih = d ? Wih_b : Wih_f;
        const float* bb  = d ? b_b   : b_f;
        float acc = bb[jj];
        #pragma unroll
        for (int e = 0; e < 32; ++e) acc = fmaf(embed[v * 32 + e], Wih[jj * 32 + e], acc);
        ws[XTG + r] = acc;
    } else if (i < AWT) {                  // dead region (keep writes for branch shape)
        ws[i] = 0.f;
    } else if (i < OWT) {                  // attn_WT[k][u]
        int r = i - AWT; int k = r >> 7, uu = r & 127;
        ws[i] = attn_W[uu * 256 + k];
    } else if (i < PWT) {                  // out_WT[k][v]
        int r = i - OWT; int k = r / 28, v = r % 28;
        ws[i] = out_W[v * 128 + k];
    } else if (i < WPK) {                  // projWT[k][u]
        int r = i - PWT; int k = r >> 7, uu = r & 127;
        ws[i] = proj_W[uu * 256 + k];
    } else {                               // weight frag packs (2 ushorts per thread)
        int i2 = (i - WPK) * 2;
        #pragma unroll
        for (int p = 0; p < 2; ++p, ++i2) {
            if (i2 < 131072) {             // enc pack (dirs f, b), K=128 bf16 hi
                int e  = i2 & 7;
                int ll = (i2 >> 3) & 63;
                int kt = (i2 >> 9) & 3;
                int ni = (i2 >> 11) & 3;
                int wv = (i2 >> 13) & 7;
                int d  = (i2 >> 16) & 1;
                int jj = (ni * 8 + wv) * 16 + (ll & 15);
                int kp = kt * 32 + ((ll >> 4) << 3) + e;
                const float* Whh = d ? Whh_b : Whh_f;
                ((ushort_t*)(ws + WPK))[i2] = f2bf(Whh[jj * 128 + kp]);
            } else if (i2 < 196608) {      // dec pack
                int j2 = i2 - 131072;
                int e  = j2 & 7;
                int ll = (j2 >> 3) & 63;
                int kt = (j2 >> 9) & 3;
                int ni = (j2 >> 11) & 3;
                int wv = (j2 >> 13) & 7;
                int jj = (ni * 8 + wv) * 16 + (ll & 15);
                int kp = kt * 32 + ((ll >> 4) << 3) + e;
                ((ushort_t*)(ws + WPK))[i2] = f2bf(Whh_d[jj * 128 + kp]);
            }
        }
    }
}

// ---------------- encoder (unchanged from round 14/15) ----------------
__global__ __launch_bounds__(512, 2) void enc_kernel(
    const int* __restrict__ src,
    const float* __restrict__ xtg_base,
    const ushort_t* __restrict__ wpk,
    float* __restrict__ hfin, float* __restrict__ cfin,
    ushort_t* __restrict__ hs)
{
    const int bx = blockIdx.x;
    const int dir = bx >> 7;
    const int b0 = (bx & 127) << 2;
    const int tid = threadIdx.x;
    const int w = tid >> 6, l = tid & 63;
    const int lg = l >> 4, col = l & 15;
    const int u = (w << 4) + col;
    const int row = lg;

    __shared__ __align__(16) ushort_t hb[2][4][144];
    __shared__ __align__(16) int tokl[256][4];

    for (int i = tid; i < 1024; i += 512)
        tokl[i >> 2][i & 3] = src[(b0 + (i & 3)) * S_ + (i >> 2)];
    for (int i = tid; i < 576; i += 512) ((uint_t*)hb)[i] = 0u;

    const float* xtg = xtg_base + dir * 14336;

    bfrag bf[4][4];
    {
        const ushort_t* wb = wpk + (((size_t)dir * 8 + w) << 13) + l * 8;
        #pragma unroll
        for (int ni = 0; ni < 4; ++ni)
            #pragma unroll
            for (int kt = 0; kt < 4; ++kt)
                bf[ni][kt] = *reinterpret_cast<const bfrag*>(wb + ((ni * 4 + kt) << 9));
    }
    __syncthreads();

    float c_reg = 0.f, h_reg = 0.f;

    f32x4 xg_cur, xg_next;
    {
        int p0 = dir ? (S_ - 1) : 0;
        xg_cur = *reinterpret_cast<const f32x4*>(xtg + ((size_t)tokl[p0][row] << 9) + (u << 2));
    }

    const bfrag zf = {0, 0, 0, 0, 0, 0, 0, 0};
    bfrag af0 = zf, af1 = zf, af2 = zf, af3 = zf;
    const bool ard = ((col & 3) == 0);
    const int ar = col >> 2;
    const int swz = ar << 3;
    const f32x4 zacc = {0.f, 0.f, 0.f, 0.f};

    ushort_t* hs_ptr = hs + ((size_t)(b0 + row) * S_ + (dir ? (S_ - 1) : 0)) * 256
                          + dir * 128 + u;
    const int hs_step = dir ? -256 : 256;

    for (int t = 0; t < S_; ++t) {
        const int cb = t & 1, nb = cb ^ 1;

        if (t + 1 < S_) {
            int pn = dir ? (S_ - 2 - t) : (t + 1);
            xg_next = *reinterpret_cast<const f32x4*>(xtg + ((size_t)tokl[pn][row] << 9) + (u << 2));
        }

        if (ard) {
            const ushort_t* hp = &hb[cb][ar][0];
            af0 = *reinterpret_cast<const bfrag*>(hp + ((  0 + (lg << 3)) ^ swz));
            af1 = *reinterpret_cast<const bfrag*>(hp + (( 32 + (lg << 3)) ^ swz));
            af2 = *reinterpret_cast<const bfrag*>(hp + (( 64 + (lg << 3)) ^ swz));
            af3 = *reinterpret_cast<const bfrag*>(hp + (( 96 + (lg << 3)) ^ swz));
        }

        f32x4 a0 = __builtin_amdgcn_mfma_f32_16x16x32_bf16(af0, bf[0][0], zacc, 0, 0, 0);
        f32x4 a1 = __builtin_amdgcn_mfma_f32_16x16x32_bf16(af0, bf[1][0], zacc, 0, 0, 0);
        f32x4 a2 = __builtin_amdgcn_mfma_f32_16x16x32_bf16(af0, bf[2][0], zacc, 0, 0, 0);
        f32x4 a3 = __builtin_amdgcn_mfma_f32_16x16x32_bf16(af0, bf[3][0], zacc, 0, 0, 0);
        #define KT1(AF, kt) { \
            a0 = __builtin_amdgcn_mfma_f32_16x16x32_bf16(AF, bf[0][kt], a0, 0, 0, 0); \
            a1 = __builtin_amdgcn_mfma_f32_16x16x32_bf16(AF, bf[1][kt], a1, 0, 0, 0); \
            a2 = __builtin_amdgcn_mfma_f32_16x16x32_bf16(AF, bf[2][kt], a2, 0, 0, 0); \
            a3 = __builtin_amdgcn_mfma_f32_16x16x32_bf16(AF, bf[3][kt], a3, 0, 0, 0); \
        }
        KT1(af1, 1) KT1(af2, 2) KT1(af3, 3)
        #undef KT1

        {
            float gi = a0[0] + xg_cur[0], gf = a1[0] + xg_cur[1];
            float gg = a2[0] + xg_cur[2], go = a3[0] + xg_cur[3];
            float ii = sigm(gi), ff = sigm(gf), gG = tanh_(gg), oo = sigm(go);
            c_reg = ff * c_reg + ii * gG;
            float h = oo * tanh_(c_reg);
            h_reg = h;
            ushort_t hi = f2bf(h);
            hb[nb][row][u ^ (row << 3)] = hi;
            *hs_ptr = hi;
            hs_ptr += hs_step;
        }
        xg_cur = xg_next;
        lds_barrier();
    }

    hfin[dir * 65536 + (b0 + row) * 128 + u] = h_reg;
    cfin[dir * 65536 + (b0 + row) * 128 + u] = c_reg;
}

// ---------------- decoder: MFMA version (enc clone, 10 steps, fp32 hdec out) ----------------
__global__ __launch_bounds__(512, 2) void dec_kernel(
    const int* __restrict__ target,
    const float* __restrict__ xtd_gi,       // ws+XTD
    const ushort_t* __restrict__ wpk,       // ws+WPK (dec pack at +131072 ushorts)
    const float* __restrict__ hfin, const float* __restrict__ cfin,
    float* __restrict__ hdec)
{
    const int b0 = blockIdx.x << 2;        // 128 blocks x 4 rows
    const int tid = threadIdx.x;
    const int w = tid >> 6, l = tid & 63;
    const int lg = l >> 4, col = l & 15;
    const int u = (w << 4) + col;
    const int row = lg;

    __shared__ __align__(16) ushort_t hb[2][4][144];
    __shared__ __align__(16) int tokl[T_][4];

    if (tid < 40) {
        int t = tid >> 2, r = tid & 3;
        tokl[t][r] = (t == 0) ? 0 : target[(b0 + r) * T_ + t - 1];
    }

    bfrag bf[4][4];
    {
        const ushort_t* wb = wpk + 131072 + ((size_t)w << 13) + l * 8;
        #pragma unroll
        for (int ni = 0; ni < 4; ++ni)
            #pragma unroll
            for (int kt = 0; kt < 4; ++kt)
                bf[ni][kt] = *reinterpret_cast<const bfrag*>(wb + ((ni * 4 + kt) << 9));
    }

    float c_reg, h_reg;
    {
        int gb = (b0 + row) * 128 + u;
        h_reg = hfin[gb] + hfin[65536 + gb];
        c_reg = cfin[gb] + cfin[65536 + gb];
        hb[0][row][u ^ (row << 3)] = f2bf(h_reg);
    }
    __syncthreads();

    const bfrag zf = {0, 0, 0, 0, 0, 0, 0, 0};
    bfrag af0 = zf, af1 = zf, af2 = zf, af3 = zf;
    const bool ard = ((col & 3) == 0);
    const int ar = col >> 2;
    const int swz = ar << 3;
    const f32x4 zacc = {0.f, 0.f, 0.f, 0.f};

    for (int t = 0; t < T_; ++t) {
        const int cb = t & 1, nb = cb ^ 1;

        f32x4 xgc = *reinterpret_cast<const f32x4*>(
            xtd_gi + ((size_t)tokl[t][row] << 9) + (u << 2));

        if (ard) {
            const ushort_t* hp = &hb[cb][ar][0];
            af0 = *reinterpret_cast<const bfrag*>(hp + ((  0 + (lg << 3)) ^ swz));
            af1 = *reinterpret_cast<const bfrag*>(hp + (( 32 + (lg << 3)) ^ swz));
            af2 = *reinterpret_cast<const bfrag*>(hp + (( 64 + (lg << 3)) ^ swz));
            af3 = *reinterpret_cast<const bfrag*>(hp + (( 96 + (lg << 3)) ^ swz));
        }

        f32x4 a0 = __builtin_amdgcn_mfma_f32_16x16x32_bf16(af0, bf[0][0], zacc, 0, 0, 0);
        f32x4 a1 = __builtin_amdgcn_mfma_f32_16x16x32_bf16(af0, bf[1][0], zacc, 0, 0, 0);
        f32x4 a2 = __builtin_amdgcn_mfma_f32_16x16x32_bf16(af0, bf[2][0], zacc, 0, 0, 0);
        f32x4 a3 = __builtin_amdgcn_mfma_f32_16x16x32_bf16(af0, bf[3][0], zacc, 0, 0, 0);
        #define KT1(AF, kt) { \
            a0 = __builtin_amdgcn_mfma_f32_16x16x32_bf16(AF, bf[0][kt], a0, 0, 0, 0); \
            a1 = __builtin_amdgcn_mfma_f32_16x16x32_bf16(AF, bf[1][kt], a1, 0, 0, 0); \
            a2 = __builtin_amdgcn_mfma_f32_16x16x32_bf16(AF, bf[2][kt], a2, 0, 0, 0); \
            a3 = __builtin_amdgcn_mfma_f32_16x16x32_bf16(AF, bf[3][kt], a3, 0, 0, 0); \
        }
        KT1(af1, 1) KT1(af2, 2) KT1(af3, 3)
        #undef KT1

        {
            float gi = a0[0] + xgc[0], gf = a1[0] + xgc[1];
            float gg = a2[0] + xgc[2], go = a3[0] + xgc[3];
            float ii = sigm(gi), ff = sigm(gf), gG = tanh_(gg), oo = sigm(go);
            c_reg = ff * c_reg + ii * gG;
            float h = oo * tanh_(c_reg);
            h_reg = h;
            hb[nb][row][u ^ (row << 3)] = f2bf(h);
            hdec[((size_t)(b0 + row) * T_ + t) * 128 + u] = h;
        }
        lds_barrier();
    }
}

// ---------------- attention: 512 thr, e-LDS, reduced LDS-op phases ----------------
#define ESW(unit, row) ((((unit) ^ ((row) & 31))) << 3)   // ushort offset within row
__global__ __launch_bounds__(512, 1) void attn_kernel(
    const float* __restrict__ hdec,
    const float* __restrict__ projW, const float* __restrict__ proj_b,
    const float* __restrict__ projWT,
    const float* __restrict__ attn_WT, const float* __restrict__ attn_b,
    const float* __restrict__ out_WT, const float* __restrict__ out_b,
    const ushort_t* __restrict__ hs, float* __restrict__ out)
{
    const int b = blockIdx.x;
    const int tid = threadIdx.x;

    __shared__ __align__(16) char smem[156672];
    ushort_t* e_lds = (ushort_t*)smem;                    // [256][256] swizzled
    float* hd   = (float*)(smem + 131072);                // [10][128]
    float* q    = (float*)(smem + 136192);                // [2560]
    float* sc   = (float*)(smem + 146432);                // [2560]
    float* part = (float*)smem;                           // alias after phase 3
    float* wsum = (float*)(smem + 40960);                 // alias [12][256]

    const ushort_t* e = hs + (size_t)b * 65536;

    // issue staged e loads into regs (latency hidden under phase 0)
    uint4 st[16];
    #pragma unroll
    for (int i = 0; i < 16; ++i)
        st[i] = *reinterpret_cast<const uint4*>(e + (i * 512 + tid) * 8);

    for (int i = tid; i < 1280; i += 512) hd[i] = hdec[(size_t)b * 1280 + i];
    lds_barrier();          // hd visible; staged e loads remain in flight

    // phase 0: q[t][d]; half 0 -> t 0..4, half 1 -> t 5..9 (swizzle-stored)
    {
        const int half = tid >> 8, d = tid & 255;
        float acc[5];
        #pragma unroll
        for (int i = 0; i < 5; ++i) acc[i] = 0.f;
        for (int k = 0; k < 128; ++k) {
            float pw = projW[k * 256 + d];
            #pragma unroll
            for (int i = 0; i < 5; ++i) acc[i] = fmaf(hd[(half * 5 + i) * 128 + k], pw, acc[i]);
        }
        int swd = d ^ ((((uint_t)d >> 5) & 7) << 2);
        #pragma unroll
        for (int i = 0; i < 5; ++i) q[(half * 5 + i) * 256 + swd] = acc[i];
    }

    // write staged e -> LDS (swizzled 16B units)
    #pragma unroll
    for (int i = 0; i < 16; ++i) {
        int idx = i * 512 + tid;
        int row = idx >> 5, c = idx & 31;
        *reinterpret_cast<uint4*>(e_lds + row * 256 + ESW(c, row)) = st[i];
    }
    lds_barrier();

    // phase 1: scores -- t-outer, e held in regs (16 + 80 LDS reads/wave)
    {
        const int w = tid >> 6, l = tid & 63;
        const int s3 = l >> 3, k8 = l & 7;
        uint4 E0[4], E1[4], E2[4], E3[4];
        #pragma unroll
        for (int p = 0; p < 4; ++p) {
            int s = w * 32 + p * 8 + s3;
            const ushort_t* lrow = e_lds + s * 256;
            E0[p] = *reinterpret_cast<const uint4*>(lrow + ESW((k8 << 2) + 0, s));
            E1[p] = *reinterpret_cast<const uint4*>(lrow + ESW((k8 << 2) + 1, s));
            E2[p] = *reinterpret_cast<const uint4*>(lrow + ESW((k8 << 2) + 2, s));
            E3[p] = *reinterpret_cast<const uint4*>(lrow + ESW((k8 << 2) + 3, s));
        }
        for (int t = 0; t < 10; ++t) {
            const float* qb = &q[t * 256];
            #define QCH(i) (*reinterpret_cast<const float4*>(&qb[(k8 * 32 + (i) * 4) ^ (k8 << 2)]))
            float4 Q0 = QCH(0), Q1 = QCH(1), Q2 = QCH(2), Q3 = QCH(3);
            float4 Q4 = QCH(4), Q5 = QCH(5), Q6 = QCH(6), Q7 = QCH(7);
            #undef QCH
            #pragma unroll
            for (int p = 0; p < 4; ++p) {
                float a = 0.f;
                #define DOT4(pa, pb, qv) { float4 q_ = (qv); \
                    a = fmaf(bflo(pa), q_.x, a); a = fmaf(bfhi(pa), q_.y, a); \
                    a = fmaf(bflo(pb), q_.z, a); a = fmaf(bfhi(pb), q_.w, a); }
                DOT4(E0[p].x, E0[p].y, Q0); DOT4(E0[p].z, E0[p].w, Q1);
                DOT4(E1[p].x, E1[p].y, Q2); DOT4(E1[p].z, E1[p].w, Q3);
                DOT4(E2[p].x, E2[p].y, Q4); DOT4(E2[p].z, E2[p].w, Q5);
                DOT4(E3[p].x, E3[p].y, Q6); DOT4(E3[p].z, E3[p].w, Q7);
                #undef DOT4
                a += __shfl_xor(a, 1);
                a += __shfl_xor(a, 2);
                a += __shfl_xor(a, 4);
                if (k8 == 0) sc[t * 256 + (w * 32 + p * 8 + s3)] = a;
            }
        }
    }
    __syncthreads();

    // phase 2: softmax (wave per t)
    {
        const int w = tid >> 6, l = tid & 63;
        for (int t = w; t < 10; t += 8) {
            float4 sv = *reinterpret_cast<const float4*>(&sc[t * 256 + l * 4]);
            float m = fmaxf(fmaxf(sv.x, sv.y), fmaxf(sv.z, sv.w));
            #pragma unroll
            for (int o = 1; o < 64; o <<= 1) m = fmaxf(m, __shfl_xor(m, o));
            float e0 = fast_exp2((sv.x - m) * 1.4426950408889634f);
            float e1 = fast_exp2((sv.y - m) * 1.4426950408889634f);
            float e2 = fast_exp2((sv.z - m) * 1.4426950408889634f);
            float e3 = fast_exp2((sv.w - m) * 1.4426950408889634f);
            float ssum = e0 + e1 + e2 + e3;
            #pragma unroll
            for (int o = 1; o < 64; o <<= 1) ssum += __shfl_xor(ssum, o);
            float inv = fast_rcp(ssum);
            *reinterpret_cast<float4*>(&sc[t * 256 + l * 4]) =
                make_float4(e0 * inv, e1 * inv, e2 * inv, e3 * inv);
        }
    }
    __syncthreads();

    // phase 3: wsum partials -- 4-s chunks, float4 sc reads (144 LDS ops/wave)
    {
        const int w = tid >> 6, l = tid & 63;
        const int chunk = w >> 1, tH = (w & 1) * 5;
        const int sbase = chunk * 64;
        const int unit = l >> 1, half2 = (l & 1) << 2;
        float ax[5], ay[5], az[5], aw2[5];
        #pragma unroll
        for (int i = 0; i < 5; ++i) { ax[i] = 0.f; ay[i] = 0.f; az[i] = 0.f; aw2[i] = 0.f; }
        for (int c4 = 0; c4 < 16; ++c4) {
            int s0 = sbase + c4 * 4;
            uint2 eA = *reinterpret_cast<const uint2*>(e_lds + (s0 + 0) * 256 + ESW(unit, s0 + 0) + half2);
            uint2 eB = *reinterpret_cast<const uint2*>(e_lds + (s0 + 1) * 256 + ESW(unit, s0 + 1) + half2);
            uint2 eC = *reinterpret_cast<const uint2*>(e_lds + (s0 + 2) * 256 + ESW(unit, s0 + 2) + half2);
            uint2 eD = *reinterpret_cast<const uint2*>(e_lds + (s0 + 3) * 256 + ESW(unit, s0 + 3) + half2);
            #pragma unroll
            for (int i = 0; i < 5; ++i) {
                float4 a4 = *reinterpret_cast<const float4*>(&sc[(tH + i) * 256 + s0]);
                ax[i]  = fmaf(bflo(eA.x), a4.x, ax[i]);  ay[i]  = fmaf(bfhi(eA.x), a4.x, ay[i]);
                az[i]  = fmaf(bflo(eA.y), a4.x, az[i]);  aw2[i] = fmaf(bfhi(eA.y), a4.x, aw2[i]);
                ax[i]  = fmaf(bflo(eB.x), a4.y, ax[i]);  ay[i]  = fmaf(bfhi(eB.x), a4.y, ay[i]);
                az[i]  = fmaf(bflo(eB.y), a4.y, az[i]);  aw2[i] = fmaf(bfhi(eB.y), a4.y, aw2[i]);
                ax[i]  = fmaf(bflo(eC.x), a4.z, ax[i]);  ay[i]  = fmaf(bfhi(eC.x), a4.z, ay[i]);
                az[i]  = fmaf(bflo(eC.y), a4.z, az[i]);  aw2[i] = fmaf(bfhi(eC.y), a4.z, aw2[i]);
                ax[i]  = fmaf(bflo(eD.x), a4.w, ax[i]);  ay[i]  = fmaf(bfhi(eD.x), a4.w, ay[i]);
                az[i]  = fmaf(bflo(eD.y), a4.w, az[i]);  aw2[i] = fmaf(bfhi(eD.y), a4.w, aw2[i]);
            }
        }
        __syncthreads();   // all e_lds reads complete before aliasing writes
        #pragma unroll
        for (int i = 0; i < 5; ++i)
            *reinterpret_cast<float4*>(&part[(chunk * 10 + tH + i) * 256 + l * 4]) =
                make_float4(ax[i], ay[i], az[i], aw2[i]);
    }
    __syncthreads();

    // phase 4: reduce partials (+zero pad rows 10,11 of wsum)
    for (int i = tid; i < 2560; i += 512)
        wsum[i] = part[i] + part[2560 + i] + part[5120 + i] + part[7680 + i];
    if (tid < 512) wsum[2560 + tid] = 0.f;
    __syncthreads();

    // phase 5: ctx[t][u] -> q[0..1280); th groups t {0-2,3-5,6-7,8-9}
    {
        const int u = tid & 127, th = tid >> 7;
        const int st5 = (th < 2) ? th * 3 : 6 + (th - 2) * 2;
        const int cn = (th < 2) ? 3 : 2;
        float acc[3];
        #pragma unroll
        for (int i = 0; i < 3; ++i) acc[i] = proj_b[u];
        for (int k = 0; k < 256; ++k) {
            float pw = projWT[k * 128 + u];
            #pragma unroll
            for (int i = 0; i < 3; ++i) acc[i] = fmaf(pw, wsum[(st5 + i) * 256 + k], acc[i]);
        }
        #pragma unroll
        for (int i = 0; i < 3; ++i)
            if (i < cn) q[(st5 + i) * 128 + u] = acc[i];
    }
    __syncthreads();

    // phase 6: comb[t][u] = tanh(...) -> q[1280..2560)
    {
        const int u = tid & 127, th = tid >> 7;
        const int st6 = (th < 2) ? th * 3 : 6 + (th - 2) * 2;
        const int cn = (th < 2) ? 3 : 2;
        float acc[3];
        #pragma unroll
        for (int i = 0; i < 3; ++i) acc[i] = attn_b[u];
        for (int k = 0; k < 128; ++k) {
            float a1 = attn_WT[k * 128 + u];
            #pragma unroll
            for (int i = 0; i < 3; ++i) {
                int tt = (st6 + i < 10) ? (st6 + i) : 9;
                acc[i] = fmaf(a1, hd[tt * 128 + k], acc[i]);
            }
        }
        for (int k = 0; k < 128; ++k) {
            float a2 = attn_WT[(128 + k) * 128 + u];
            #pragma unroll
            for (int i = 0; i < 3; ++i) {
                int tt = (st6 + i < 10) ? (st6 + i) : 9;
                acc[i] = fmaf(a2, q[tt * 128 + k], acc[i]);
            }
        }
        #pragma unroll
        for (int i = 0; i < 3; ++i)
            if (i < cn) q[1280 + (st6 + i) * 128 + u] = tanh_(acc[i]);
    }
    __syncthreads();

    // phase 7: logits
    for (int o = tid; o < 280; o += 512) {
        int t = o / 28, v = o - t * 28;
        float acc = out_b[v];
        #pragma unroll 4
        for (int k = 0; k < 128; ++k)
            acc = fmaf(out_WT[k * 28 + v], q[1280 + t * 128 + k], acc);
        out[(size_t)b * 280 + o] = acc;
    }
}

extern "C" void kernel_launch(void* const* d_in, const int* in_sizes, int n_in,
                              void* d_out, int out_size, void* d_ws, size_t ws_size,
                              hipStream_t stream) {
    const int* src      = (const int*)d_in[0];
    const int* target   = (const int*)d_in[1];
    const float* embed  = (const float*)d_in[2];
    const float* Wih_f  = (const float*)d_in[3];
    const float* Whh_f  = (const float*)d_in[4];
    const float* b_f    = (const float*)d_in[5];
    const float* Wih_b  = (const float*)d_in[6];
    const float* Whh_b  = (const float*)d_in[7];
    const float* b_b    = (const float*)d_in[8];
    const float* Wih_d  = (const float*)d_in[9];
    const float* Whh_d  = (const float*)d_in[10];
    const float* b_d    = (const float*)d_in[11];
    const float* proj_W = (const float*)d_in[12];
    const float* proj_b = (const float*)d_in[13];
    const float* attn_W = (const float*)d_in[14];
    const float* attn_b = (const float*)d_in[15];
    const float* out_W  = (const float*)d_in[16];
    const float* out_b  = (const float*)d_in[17];

    float* ws = (float*)d_ws;
    ushort_t* hs = (ushort_t*)((char*)d_ws + HS_BYTE_OFF);
    float* out = (float*)d_out;

    prep_kernel<<<(PREP_N + 255) / 256, 256, 0, stream>>>(
        embed, Wih_f, b_f, Wih_b, b_b, Wih_d, b_d,
        Whh_f, Whh_b, Whh_d, attn_W, out_W, proj_W, ws);

    enc_kernel<<<256, 512, 0, stream>>>(
        src, ws + XTG, (const ushort_t*)(ws + WPK),
        ws + HFIN, ws + CFIN, hs);

    dec_kernel<<<128, 512, 0, stream>>>(
        target, ws + XTD, (const ushort_t*)(ws + WPK),
        ws + HFIN, ws + CFIN, ws + HDEC);

    attn_kernel<<<512, 512, 0, stream>>>(
        ws + HDEC, proj_W, proj_b, ws + PWT, ws + AWT, attn_b,
        ws + OWT, out_b, hs, out);
}

// Round 17
// 254.588 us; speedup vs baseline: 1.4186x; 1.0393x over previous
//
#include <hip/hip_runtime.h>
#include <hip/hip_bf16.h>
#include <stdint.h>

typedef unsigned short ushort_t;
typedef unsigned int uint_t;
typedef __attribute__((ext_vector_type(8))) short bfrag;   // 8 bf16 = 4 VGPR
typedef __attribute__((ext_vector_type(4))) float f32x4;

#define B_ 512
#define S_ 256
#define T_ 10
#define V_ 28
#define H_ 128

// ---- workspace layout (float element offsets) ----
#define XTD 0         // dec xg gate-interleaved [28][128][4]
#define XTG 14336     // enc xg gate-interleaved [2][28][128][4]
#define WTD 43008     // (dead; kept for prep branch boundaries)
#define AWT 108544    // attn_WT [256][128]
#define OWT 141312    // out_WT [128][28]
#define PWT 144896    // projWT [256][128]
#define WPK 177664    // frag packs: enc f,b = ushort[0..131072), dec = [131072..196608)
#define HFIN 308736
#define CFIN 439808
#define HDEC 570880
#define HS_BYTE_OFF (1226240ull * 4ull)
#define PREP_N 308736

__device__ __forceinline__ float fast_exp2(float x) { return __builtin_amdgcn_exp2f(x); }
__device__ __forceinline__ float fast_rcp(float x)  { return __builtin_amdgcn_rcpf(x); }
__device__ __forceinline__ float sigm(float x) {
    return fast_rcp(1.f + fast_exp2(-1.4426950408889634f * x));
}
__device__ __forceinline__ float tanh_(float x) {
    return 1.f - 2.f * fast_rcp(1.f + fast_exp2(2.8853900817779268f * x));
}
__device__ __forceinline__ ushort_t f2bf(float x) {
    uint_t u = __float_as_uint(x);
    return (ushort_t)((u + 0x7FFFu + ((u >> 16) & 1u)) >> 16);  // RNE
}
__device__ __forceinline__ float bflo(uint_t u) { return __uint_as_float(u << 16); }
__device__ __forceinline__ float bfhi(uint_t u) { return __uint_as_float(u & 0xFFFF0000u); }

// LDS-only barrier: drain LDS ops, sync, fence scheduler (rule #18).
__device__ __forceinline__ void lds_barrier() {
    asm volatile("s_waitcnt lgkmcnt(0)" ::: "memory");
    __builtin_amdgcn_s_barrier();
    __builtin_amdgcn_sched_barrier(0);
}

// ---------------- prep (unchanged from round 16) ----------------
__global__ __launch_bounds__(256) void prep_kernel(
    const float* __restrict__ embed,
    const float* __restrict__ Wih_f, const float* __restrict__ b_f,
    const float* __restrict__ Wih_b, const float* __restrict__ b_b,
    const float* __restrict__ Wih_d, const float* __restrict__ b_d,
    const float* __restrict__ Whh_f, const float* __restrict__ Whh_b,
    const float* __restrict__ Whh_d,
    const float* __restrict__ attn_W, const float* __restrict__ out_W,
    const float* __restrict__ proj_W,
    float* __restrict__ ws)
{
    int i = blockIdx.x * 256 + threadIdx.x;
    if (i < XTG) {                         // dec xg gate-interleaved [v][u][g]
        int v = i >> 9, q = i & 511;
        int uu = q >> 2, g = q & 3;
        int jj = g * 128 + uu;
        float acc = b_d[jj];
        #pragma unroll
        for (int e = 0; e < 32; ++e) acc = fmaf(embed[v * 32 + e], Wih_d[jj * 32 + e], acc);
        ws[XTD + i] = acc;
    } else if (i < WTD) {                  // enc xg gate-interleaved: [d][v][u][g]
        int r = i - XTG; int d = r / 14336; int rem = r % 14336;
        int v = rem >> 9, q = rem & 511;
        int uu = q >> 2, g = q & 3;
        int jj = g * 128 + uu;
        const float* Wih = d ? Wih_b : Wih_f;
        const float* bb  = d ? b_b   : b_f;
        float acc = bb[jj];
        #pragma unroll
        for (int e = 0; e < 32; ++e) acc = fmaf(embed[v * 32 + e], Wih[jj * 32 + e], acc);
        ws[XTG + r] = acc;
    } else if (i < AWT) {
        ws[i] = 0.f;
    } else if (i < OWT) {                  // attn_WT[k][u]
        int r = i - AWT; int k = r >> 7, uu = r & 127;
        ws[i] = attn_W[uu * 256 + k];
    } else if (i < PWT) {                  // out_WT[k][v]
        int r = i - OWT; int k = r / 28, v = r % 28;
        ws[i] = out_W[v * 128 + k];
    } else if (i < WPK) {                  // projWT[k][u]
        int r = i - PWT; int k = r >> 7, uu = r & 127;
        ws[i] = proj_W[uu * 256 + k];
    } else {                               // weight frag packs (2 ushorts per thread)
        int i2 = (i - WPK) * 2;
        #pragma unroll
        for (int p = 0; p < 2; ++p, ++i2) {
            if (i2 < 131072) {             // enc pack (dirs f, b), K=128 bf16 hi
                int e  = i2 & 7;
                int ll = (i2 >> 3) & 63;
                int kt = (i2 >> 9) & 3;
                int ni = (i2 >> 11) & 3;
                int wv = (i2 >> 13) & 7;
                int d  = (i2 >> 16) & 1;
                int jj = (ni * 8 + wv) * 16 + (ll & 15);
                int kp = kt * 32 + ((ll >> 4) << 3) + e;
                const float* Whh = d ? Whh_b : Whh_f;
                ((ushort_t*)(ws + WPK))[i2] = f2bf(Whh[jj * 128 + kp]);
            } else if (i2 < 196608) {      // dec pack
                int j2 = i2 - 131072;
                int e  = j2 & 7;
                int ll = (j2 >> 3) & 63;
                int kt = (j2 >> 9) & 3;
                int ni = (j2 >> 11) & 3;
                int wv = (j2 >> 13) & 7;
                int jj = (ni * 8 + wv) * 16 + (ll & 15);
                int kp = kt * 32 + ((ll >> 4) << 3) + e;
                ((ushort_t*)(ws + WPK))[i2] = f2bf(Whh_d[jj * 128 + kp]);
            }
        }
    }
}

// ---------------- encoder: addr-hoisted, setprio'd MFMA cluster ----------------
__global__ __launch_bounds__(512, 2) void enc_kernel(
    const int* __restrict__ src,
    const float* __restrict__ xtg_base,
    const ushort_t* __restrict__ wpk,
    float* __restrict__ hfin, float* __restrict__ cfin,
    ushort_t* __restrict__ hs)
{
    const int bx = blockIdx.x;
    const int dir = bx >> 7;
    const int b0 = (bx & 127) << 2;
    const int tid = threadIdx.x;
    const int w = tid >> 6, l = tid & 63;
    const int lg = l >> 4, col = l & 15;
    const int u = (w << 4) + col;
    const int row = lg;

    __shared__ __align__(16) ushort_t hb[2][4][144];
    __shared__ __align__(16) int tokl[256][4];

    for (int i = tid; i < 1024; i += 512)
        tokl[i >> 2][i & 3] = src[(b0 + (i & 3)) * S_ + (i >> 2)];
    for (int i = tid; i < 576; i += 512) ((uint_t*)hb)[i] = 0u;

    const float* xtg = xtg_base + dir * 14336;

    bfrag bf[4][4];
    {
        const ushort_t* wb = wpk + (((size_t)dir * 8 + w) << 13) + l * 8;
        #pragma unroll
        for (int ni = 0; ni < 4; ++ni)
            #pragma unroll
            for (int kt = 0; kt < 4; ++kt)
                bf[ni][kt] = *reinterpret_cast<const bfrag*>(wb + ((ni * 4 + kt) << 9));
    }
    __syncthreads();

    float c_reg = 0.f, h_reg = 0.f;

    f32x4 xg_cur, xg_next;
    {
        int p0 = dir ? (S_ - 1) : 0;
        xg_cur = *reinterpret_cast<const f32x4*>(xtg + ((size_t)tokl[p0][row] << 9) + (u << 2));
    }

    const bfrag zf = {0, 0, 0, 0, 0, 0, 0, 0};
    bfrag af0 = zf, af1 = zf, af2 = zf, af3 = zf;
    const bool ard = ((col & 3) == 0);
    const int ar = col >> 2;
    const int swz = ar << 3;
    const f32x4 zacc = {0.f, 0.f, 0.f, 0.f};

    // hoisted A-read addresses (8: 2 buffers x 4 K-frags) and hb-write addrs (2)
    const ushort_t* ap0[4]; const ushort_t* ap1[4];
    #pragma unroll
    for (int kt = 0; kt < 4; ++kt) {
        int off = ((kt << 5) + (lg << 3)) ^ swz;
        ap0[kt] = &hb[0][ar][0] + off;
        ap1[kt] = &hb[1][ar][0] + off;
    }
    ushort_t* const hw0 = &hb[0][row][u ^ (row << 3)];
    ushort_t* const hw1 = &hb[1][row][u ^ (row << 3)];

    ushort_t* hs_ptr = hs + ((size_t)(b0 + row) * S_ + (dir ? (S_ - 1) : 0)) * 256
                          + dir * 128 + u;
    const int hs_step = dir ? -256 : 256;

    for (int t = 0; t < S_; ++t) {
        const int cb = t & 1;

        if (t + 1 < S_) {
            int pn = dir ? (S_ - 2 - t) : (t + 1);
            xg_next = *reinterpret_cast<const f32x4*>(xtg + ((size_t)tokl[pn][row] << 9) + (u << 2));
        }

        if (ard) {
            af0 = *reinterpret_cast<const bfrag*>(cb ? ap1[0] : ap0[0]);
            af1 = *reinterpret_cast<const bfrag*>(cb ? ap1[1] : ap0[1]);
            af2 = *reinterpret_cast<const bfrag*>(cb ? ap1[2] : ap0[2]);
            af3 = *reinterpret_cast<const bfrag*>(cb ? ap1[3] : ap0[3]);
        }

        __builtin_amdgcn_s_setprio(1);
        f32x4 a0 = __builtin_amdgcn_mfma_f32_16x16x32_bf16(af0, bf[0][0], zacc, 0, 0, 0);
        f32x4 a1 = __builtin_amdgcn_mfma_f32_16x16x32_bf16(af0, bf[1][0], zacc, 0, 0, 0);
        f32x4 a2 = __builtin_amdgcn_mfma_f32_16x16x32_bf16(af0, bf[2][0], zacc, 0, 0, 0);
        f32x4 a3 = __builtin_amdgcn_mfma_f32_16x16x32_bf16(af0, bf[3][0], zacc, 0, 0, 0);
        #define KT1(AF, kt) { \
            a0 = __builtin_amdgcn_mfma_f32_16x16x32_bf16(AF, bf[0][kt], a0, 0, 0, 0); \
            a1 = __builtin_amdgcn_mfma_f32_16x16x32_bf16(AF, bf[1][kt], a1, 0, 0, 0); \
            a2 = __builtin_amdgcn_mfma_f32_16x16x32_bf16(AF, bf[2][kt], a2, 0, 0, 0); \
            a3 = __builtin_amdgcn_mfma_f32_16x16x32_bf16(AF, bf[3][kt], a3, 0, 0, 0); \
        }
        KT1(af1, 1) KT1(af2, 2) KT1(af3, 3)
        #undef KT1
        __builtin_amdgcn_s_setprio(0);

        {
            float gi = a0[0] + xg_cur[0], gf = a1[0] + xg_cur[1];
            float gg = a2[0] + xg_cur[2], go = a3[0] + xg_cur[3];
            float ii = sigm(gi), ff = sigm(gf), gG = tanh_(gg), oo = sigm(go);
            c_reg = ff * c_reg + ii * gG;
            float h = oo * tanh_(c_reg);
            h_reg = h;
            ushort_t hi = f2bf(h);
            *(cb ? hw0 : hw1) = hi;        // write into buffer nb = cb^1
            *hs_ptr = hi;
            hs_ptr += hs_step;
        }
        xg_cur = xg_next;
        lds_barrier();
    }

    hfin[dir * 65536 + (b0 + row) * 128 + u] = h_reg;
    cfin[dir * 65536 + (b0 + row) * 128 + u] = c_reg;
}

// ---------------- decoder: MFMA version (unchanged from round 16) ----------------
__global__ __launch_bounds__(512, 2) void dec_kernel(
    const int* __restrict__ target,
    const float* __restrict__ xtd_gi,
    const ushort_t* __restrict__ wpk,
    const float* __restrict__ hfin, const float* __restrict__ cfin,
    float* __restrict__ hdec)
{
    const int b0 = blockIdx.x << 2;
    const int tid = threadIdx.x;
    const int w = tid >> 6, l = tid & 63;
    const int lg = l >> 4, col = l & 15;
    const int u = (w << 4) + col;
    const int row = lg;

    __shared__ __align__(16) ushort_t hb[2][4][144];
    __shared__ __align__(16) int tokl[T_][4];

    if (tid < 40) {
        int t = tid >> 2, r = tid & 3;
        tokl[t][r] = (t == 0) ? 0 : target[(b0 + r) * T_ + t - 1];
    }

    bfrag bf[4][4];
    {
        const ushort_t* wb = wpk + 131072 + ((size_t)w << 13) + l * 8;
        #pragma unroll
        for (int ni = 0; ni < 4; ++ni)
            #pragma unroll
            for (int kt = 0; kt < 4; ++kt)
                bf[ni][kt] = *reinterpret_cast<const bfrag*>(wb + ((ni * 4 + kt) << 9));
    }

    float c_reg, h_reg;
    {
        int gb = (b0 + row) * 128 + u;
        h_reg = hfin[gb] + hfin[65536 + gb];
        c_reg = cfin[gb] + cfin[65536 + gb];
        hb[0][row][u ^ (row << 3)] = f2bf(h_reg);
    }
    __syncthreads();

    const bfrag zf = {0, 0, 0, 0, 0, 0, 0, 0};
    bfrag af0 = zf, af1 = zf, af2 = zf, af3 = zf;
    const bool ard = ((col & 3) == 0);
    const int ar = col >> 2;
    const int swz = ar << 3;
    const f32x4 zacc = {0.f, 0.f, 0.f, 0.f};

    for (int t = 0; t < T_; ++t) {
        const int cb = t & 1, nb = cb ^ 1;

        f32x4 xgc = *reinterpret_cast<const f32x4*>(
            xtd_gi + ((size_t)tokl[t][row] << 9) + (u << 2));

        if (ard) {
            const ushort_t* hp = &hb[cb][ar][0];
            af0 = *reinterpret_cast<const bfrag*>(hp + ((  0 + (lg << 3)) ^ swz));
            af1 = *reinterpret_cast<const bfrag*>(hp + (( 32 + (lg << 3)) ^ swz));
            af2 = *reinterpret_cast<const bfrag*>(hp + (( 64 + (lg << 3)) ^ swz));
            af3 = *reinterpret_cast<const bfrag*>(hp + (( 96 + (lg << 3)) ^ swz));
        }

        f32x4 a0 = __builtin_amdgcn_mfma_f32_16x16x32_bf16(af0, bf[0][0], zacc, 0, 0, 0);
        f32x4 a1 = __builtin_amdgcn_mfma_f32_16x16x32_bf16(af0, bf[1][0], zacc, 0, 0, 0);
        f32x4 a2 = __builtin_amdgcn_mfma_f32_16x16x32_bf16(af0, bf[2][0], zacc, 0, 0, 0);
        f32x4 a3 = __builtin_amdgcn_mfma_f32_16x16x32_bf16(af0, bf[3][0], zacc, 0, 0, 0);
        #define KT1(AF, kt) { \
            a0 = __builtin_amdgcn_mfma_f32_16x16x32_bf16(AF, bf[0][kt], a0, 0, 0, 0); \
            a1 = __builtin_amdgcn_mfma_f32_16x16x32_bf16(AF, bf[1][kt], a1, 0, 0, 0); \
            a2 = __builtin_amdgcn_mfma_f32_16x16x32_bf16(AF, bf[2][kt], a2, 0, 0, 0); \
            a3 = __builtin_amdgcn_mfma_f32_16x16x32_bf16(AF, bf[3][kt], a3, 0, 0, 0); \
        }
        KT1(af1, 1) KT1(af2, 2) KT1(af3, 3)
        #undef KT1

        {
            float gi = a0[0] + xgc[0], gf = a1[0] + xgc[1];
            float gg = a2[0] + xgc[2], go = a3[0] + xgc[3];
            float ii = sigm(gi), ff = sigm(gf), gG = tanh_(gg), oo = sigm(go);
            c_reg = ff * c_reg + ii * gG;
            float h = oo * tanh_(c_reg);
            h_reg = h;
            hb[nb][row][u ^ (row << 3)] = f2bf(h);
            hdec[((size_t)(b0 + row) * T_ + t) * 128 + u] = h;
        }
        lds_barrier();
    }
}

// ---------------- attention: 512 thr, e-LDS, merged weight phases ----------------
#define ESW(unit, row) ((((unit) ^ ((row) & 31))) << 3)   // ushort offset within row
__global__ __launch_bounds__(512, 1) void attn_kernel(
    const float* __restrict__ hdec,
    const float* __restrict__ projW, const float* __restrict__ proj_b,
    const float* __restrict__ projWT,
    const float* __restrict__ attn_WT, const float* __restrict__ attn_b,
    const float* __restrict__ out_WT, const float* __restrict__ out_b,
    const ushort_t* __restrict__ hs, float* __restrict__ out)
{
    const int b = blockIdx.x;
    const int tid = threadIdx.x;

    __shared__ __align__(16) char smem[156672];
    ushort_t* e_lds = (ushort_t*)smem;                    // [256][256] swizzled
    float* hd   = (float*)(smem + 131072);                // [10][128]
    float* q    = (float*)(smem + 136192);                // [2560]
    float* sc   = (float*)(smem + 146432);                // [2560]
    float* part = (float*)smem;                           // alias after phase 3
    float* wsum = (float*)(smem + 40960);                 // alias [12][256]

    const ushort_t* e = hs + (size_t)b * 65536;

    // issue staged e loads into regs (latency hidden under phase 0)
    uint4 st[16];
    #pragma unroll
    for (int i = 0; i < 16; ++i)
        st[i] = *reinterpret_cast<const uint4*>(e + (i * 512 + tid) * 8);

    for (int i = tid; i < 1280; i += 512) hd[i] = hdec[(size_t)b * 1280 + i];
    lds_barrier();          // hd visible; staged e loads remain in flight

    // phase 0: q[t][d]; half 0 -> t 0..4, half 1 -> t 5..9 (swizzle-stored)
    {
        const int half = tid >> 8, d = tid & 255;
        float acc[5];
        #pragma unroll
        for (int i = 0; i < 5; ++i) acc[i] = 0.f;
        for (int k = 0; k < 128; ++k) {
            float pw = projW[k * 256 + d];
            #pragma unroll
            for (int i = 0; i < 5; ++i) acc[i] = fmaf(hd[(half * 5 + i) * 128 + k], pw, acc[i]);
        }
        int swd = d ^ ((((uint_t)d >> 5) & 7) << 2);
        #pragma unroll
        for (int i = 0; i < 5; ++i) q[(half * 5 + i) * 256 + swd] = acc[i];
    }

    // write staged e -> LDS (swizzled 16B units)
    #pragma unroll
    for (int i = 0; i < 16; ++i) {
        int idx = i * 512 + tid;
        int row = idx >> 5, c = idx & 31;
        *reinterpret_cast<uint4*>(e_lds + row * 256 + ESW(c, row)) = st[i];
    }
    lds_barrier();

    // phase 1: scores -- t-outer, e held in regs
    {
        const int w = tid >> 6, l = tid & 63;
        const int s3 = l >> 3, k8 = l & 7;
        uint4 E0[4], E1[4], E2[4], E3[4];
        #pragma unroll
        for (int p = 0; p < 4; ++p) {
            int s = w * 32 + p * 8 + s3;
            const ushort_t* lrow = e_lds + s * 256;
            E0[p] = *reinterpret_cast<const uint4*>(lrow + ESW((k8 << 2) + 0, s));
            E1[p] = *reinterpret_cast<const uint4*>(lrow + ESW((k8 << 2) + 1, s));
            E2[p] = *reinterpret_cast<const uint4*>(lrow + ESW((k8 << 2) + 2, s));
            E3[p] = *reinterpret_cast<const uint4*>(lrow + ESW((k8 << 2) + 3, s));
        }
        for (int t = 0; t < 10; ++t) {
            const float* qb = &q[t * 256];
            #define QCH(i) (*reinterpret_cast<const float4*>(&qb[(k8 * 32 + (i) * 4) ^ (k8 << 2)]))
            float4 Q0 = QCH(0), Q1 = QCH(1), Q2 = QCH(2), Q3 = QCH(3);
            float4 Q4 = QCH(4), Q5 = QCH(5), Q6 = QCH(6), Q7 = QCH(7);
            #undef QCH
            #pragma unroll
            for (int p = 0; p < 4; ++p) {
                float a = 0.f;
                #define DOT4(pa, pb, qv) { float4 q_ = (qv); \
                    a = fmaf(bflo(pa), q_.x, a); a = fmaf(bfhi(pa), q_.y, a); \
                    a = fmaf(bflo(pb), q_.z, a); a = fmaf(bfhi(pb), q_.w, a); }
                DOT4(E0[p].x, E0[p].y, Q0); DOT4(E0[p].z, E0[p].w, Q1);
                DOT4(E1[p].x, E1[p].y, Q2); DOT4(E1[p].z, E1[p].w, Q3);
                DOT4(E2[p].x, E2[p].y, Q4); DOT4(E2[p].z, E2[p].w, Q5);
                DOT4(E3[p].x, E3[p].y, Q6); DOT4(E3[p].z, E3[p].w, Q7);
                #undef DOT4
                a += __shfl_xor(a, 1);
                a += __shfl_xor(a, 2);
                a += __shfl_xor(a, 4);
                if (k8 == 0) sc[t * 256 + (w * 32 + p * 8 + s3)] = a;
            }
        }
    }
    __syncthreads();

    // phase 2: softmax (wave per t)
    {
        const int w = tid >> 6, l = tid & 63;
        for (int t = w; t < 10; t += 8) {
            float4 sv = *reinterpret_cast<const float4*>(&sc[t * 256 + l * 4]);
            float m = fmaxf(fmaxf(sv.x, sv.y), fmaxf(sv.z, sv.w));
            #pragma unroll
            for (int o = 1; o < 64; o <<= 1) m = fmaxf(m, __shfl_xor(m, o));
            float e0 = fast_exp2((sv.x - m) * 1.4426950408889634f);
            float e1 = fast_exp2((sv.y - m) * 1.4426950408889634f);
            float e2 = fast_exp2((sv.z - m) * 1.4426950408889634f);
            float e3 = fast_exp2((sv.w - m) * 1.4426950408889634f);
            float ssum = e0 + e1 + e2 + e3;
            #pragma unroll
            for (int o = 1; o < 64; o <<= 1) ssum += __shfl_xor(ssum, o);
            float inv = fast_rcp(ssum);
            *reinterpret_cast<float4*>(&sc[t * 256 + l * 4]) =
                make_float4(e0 * inv, e1 * inv, e2 * inv, e3 * inv);
        }
    }
    __syncthreads();

    // phase 3: wsum partials -- 4-s chunks, float4 sc reads
    {
        const int w = tid >> 6, l = tid & 63;
        const int chunk = w >> 1, tH = (w & 1) * 5;
        const int sbase = chunk * 64;
        const int unit = l >> 1, half2 = (l & 1) << 2;
        float ax[5], ay[5], az[5], aw2[5];
        #pragma unroll
        for (int i = 0; i < 5; ++i) { ax[i] = 0.f; ay[i] = 0.f; az[i] = 0.f; aw2[i] = 0.f; }
        for (int c4 = 0; c4 < 16; ++c4) {
            int s0 = sbase + c4 * 4;
            uint2 eA = *reinterpret_cast<const uint2*>(e_lds + (s0 + 0) * 256 + ESW(unit, s0 + 0) + half2);
            uint2 eB = *reinterpret_cast<const uint2*>(e_lds + (s0 + 1) * 256 + ESW(unit, s0 + 1) + half2);
            uint2 eC = *reinterpret_cast<const uint2*>(e_lds + (s0 + 2) * 256 + ESW(unit, s0 + 2) + half2);
            uint2 eD = *reinterpret_cast<const uint2*>(e_lds + (s0 + 3) * 256 + ESW(unit, s0 + 3) + half2);
            #pragma unroll
            for (int i = 0; i < 5; ++i) {
                float4 a4 = *reinterpret_cast<const float4*>(&sc[(tH + i) * 256 + s0]);
                ax[i]  = fmaf(bflo(eA.x), a4.x, ax[i]);  ay[i]  = fmaf(bfhi(eA.x), a4.x, ay[i]);
                az[i]  = fmaf(bflo(eA.y), a4.x, az[i]);  aw2[i] = fmaf(bfhi(eA.y), a4.x, aw2[i]);
                ax[i]  = fmaf(bflo(eB.x), a4.y, ax[i]);  ay[i]  = fmaf(bfhi(eB.x), a4.y, ay[i]);
                az[i]  = fmaf(bflo(eB.y), a4.y, az[i]);  aw2[i] = fmaf(bfhi(eB.y), a4.y, aw2[i]);
                ax[i]  = fmaf(bflo(eC.x), a4.z, ax[i]);  ay[i]  = fmaf(bfhi(eC.x), a4.z, ay[i]);
                az[i]  = fmaf(bflo(eC.y), a4.z, az[i]);  aw2[i] = fmaf(bfhi(eC.y), a4.z, aw2[i]);
                ax[i]  = fmaf(bflo(eD.x), a4.w, ax[i]);  ay[i]  = fmaf(bfhi(eD.x), a4.w, ay[i]);
                az[i]  = fmaf(bflo(eD.y), a4.w, az[i]);  aw2[i] = fmaf(bfhi(eD.y), a4.w, aw2[i]);
            }
        }
        __syncthreads();
        #pragma unroll
        for (int i = 0; i < 5; ++i)
            *reinterpret_cast<float4*>(&part[(chunk * 10 + tH + i) * 256 + l * 4]) =
                make_float4(ax[i], ay[i], az[i], aw2[i]);
    }
    __syncthreads();

    // phase 4: reduce partials (+zero pad rows 10,11 of wsum)
    for (int i = tid; i < 2560; i += 512)
        wsum[i] = part[i] + part[2560 + i] + part[5120 + i] + part[7680 + i];
    if (tid < 512) wsum[2560 + tid] = 0.f;
    __syncthreads();

    // phase 5+6a merged: ctx accumulation (projWT, 256k) + comb's h-half (attn_WT, 128k)
    // th groups t {0-2,3-5,6-7,8-9}
    {
        const int u = tid & 127, th = tid >> 7;
        const int st5 = (th < 2) ? th * 3 : 6 + (th - 2) * 2;
        const int cn = (th < 2) ? 3 : 2;
        float acc[3], accc[3];
        #pragma unroll
        for (int i = 0; i < 3; ++i) { acc[i] = proj_b[u]; accc[i] = attn_b[u]; }
        for (int k = 0; k < 128; ++k) {
            float pw1 = projWT[k * 128 + u];
            float pw2 = projWT[(128 + k) * 128 + u];
            float a1 = attn_WT[k * 128 + u];
            #pragma unroll
            for (int i = 0; i < 3; ++i) {
                int tt = (st5 + i < 10) ? (st5 + i) : 9;
                acc[i] = fmaf(pw1, wsum[(st5 + i) * 256 + k], acc[i]);
                acc[i] = fmaf(pw2, wsum[(st5 + i) * 256 + 128 + k], acc[i]);
                accc[i] = fmaf(a1, hd[tt * 128 + k], accc[i]);
            }
        }
        #pragma unroll
        for (int i = 0; i < 3; ++i)
            if (i < cn) {
                q[(st5 + i) * 128 + u] = acc[i];          // ctx
                sc[(st5 + i) * 128 + u] = accc[i];        // comb partial (reuse sc)
            }
    }
    __syncthreads();

    // phase 6b: comb = tanh(partial + attn_W2 . ctx) -> q[1280..2560)
    {
        const int u = tid & 127, th = tid >> 7;
        const int st6 = (th < 2) ? th * 3 : 6 + (th - 2) * 2;
        const int cn = (th < 2) ? 3 : 2;
        float acc[3];
        #pragma unroll
        for (int i = 0; i < 3; ++i) {
            int tt = (st6 + i < 10) ? (st6 + i) : 9;
            acc[i] = sc[tt * 128 + u];
        }
        for (int k = 0; k < 128; ++k) {
            float a2 = attn_WT[(128 + k) * 128 + u];
            #pragma unroll
            for (int i = 0; i < 3; ++i) {
                int tt = (st6 + i < 10) ? (st6 + i) : 9;
                acc[i] = fmaf(a2, q[tt * 128 + k], acc[i]);
            }
        }
        #pragma unroll
        for (int i = 0; i < 3; ++i)
            if (i < cn) q[1280 + (st6 + i) * 128 + u] = tanh_(acc[i]);
    }
    __syncthreads();

    // phase 7: logits
    for (int o = tid; o < 280; o += 512) {
        int t = o / 28, v = o - t * 28;
        float acc = out_b[v];
        #pragma unroll 4
        for (int k = 0; k < 128; ++k)
            acc = fmaf(out_WT[k * 28 + v], q[1280 + t * 128 + k], acc);
        out[(size_t)b * 280 + o] = acc;
    }
}

extern "C" void kernel_launch(void* const* d_in, const int* in_sizes, int n_in,
                              void* d_out, int out_size, void* d_ws, size_t ws_size,
                              hipStream_t stream) {
    const int* src      = (const int*)d_in[0];
    const int* target   = (const int*)d_in[1];
    const float* embed  = (const float*)d_in[2];
    const float* Wih_f  = (const float*)d_in[3];
    const float* Whh_f  = (const float*)d_in[4];
    const float* b_f    = (const float*)d_in[5];
    const float* Wih_b  = (const float*)d_in[6];
    const float* Whh_b  = (const float*)d_in[7];
    const float* b_b    = (const float*)d_in[8];
    const float* Wih_d  = (const float*)d_in[9];
    const float* Whh_d  = (const float*)d_in[10];
    const float* b_d    = (const float*)d_in[11];
    const float* proj_W = (const float*)d_in[12];
    const float* proj_b = (const float*)d_in[13];
    const float* attn_W = (const float*)d_in[14];
    const float* attn_b = (const float*)d_in[15];
    const float* out_W  = (const float*)d_in[16];
    const float* out_b  = (const float*)d_in[17];

    float* ws = (float*)d_ws;
    ushort_t* hs = (ushort_t*)((char*)d_ws + HS_BYTE_OFF);
    float* out = (float*)d_out;

    prep_kernel<<<(PREP_N + 255) / 256, 256, 0, stream>>>(
        embed, Wih_f, b_f, Wih_b, b_b, Wih_d, b_d,
        Whh_f, Whh_b, Whh_d, attn_W, out_W, proj_W, ws);

    enc_kernel<<<256, 512, 0, stream>>>(
        src, ws + XTG, (const ushort_t*)(ws + WPK),
        ws + HFIN, ws + CFIN, hs);

    dec_kernel<<<128, 512, 0, stream>>>(
        target, ws + XTD, (const ushort_t*)(ws + WPK),
        ws + HFIN, ws + CFIN, ws + HDEC);

    attn_kernel<<<512, 512, 0, stream>>>(
        ws + HDEC, proj_W, proj_b, ws + PWT, ws + AWT, attn_b,
        ws + OWT, out_b, hs, out);
}

// Round 18
// 229.144 us; speedup vs baseline: 1.5761x; 1.1110x over previous
//
#include <hip/hip_runtime.h>
#include <hip/hip_bf16.h>
#include <stdint.h>

typedef unsigned short ushort_t;
typedef unsigned int uint_t;
typedef __attribute__((ext_vector_type(8))) short bfrag;   // 8 bf16 = 4 VGPR
typedef __attribute__((ext_vector_type(4))) float f32x4;

#define B_ 512
#define S_ 256
#define T_ 10
#define V_ 28
#define H_ 128

// ---- workspace layout (float element offsets) ----
#define XTD 0         // dec xg gate-interleaved [28][128][4]
#define XTG 14336     // enc xg gate-interleaved [2][28][128][4]
#define WTD 43008     // (dead; kept for prep branch boundaries)
#define AWT 108544    // attn_WT [256][128]
#define OWT 141312    // out_WT [128][28]
#define PWT 144896    // projWT [256][128]
#define WPK 177664    // frag packs: enc f,b = ushort[0..131072), dec = [131072..196608)
#define HFIN 308736
#define CFIN 439808
#define HDEC 570880
#define HS_BYTE_OFF (1226240ull * 4ull)
#define PREP_N 308736

__device__ __forceinline__ float fast_exp2(float x) { return __builtin_amdgcn_exp2f(x); }
__device__ __forceinline__ float fast_rcp(float x)  { return __builtin_amdgcn_rcpf(x); }
__device__ __forceinline__ float sigm(float x) {
    return fast_rcp(1.f + fast_exp2(-1.4426950408889634f * x));
}
__device__ __forceinline__ float tanh_(float x) {
    return 1.f - 2.f * fast_rcp(1.f + fast_exp2(2.8853900817779268f * x));
}
__device__ __forceinline__ ushort_t f2bf(float x) {
    uint_t u = __float_as_uint(x);
    return (ushort_t)((u + 0x7FFFu + ((u >> 16) & 1u)) >> 16);  // RNE
}
__device__ __forceinline__ float bflo(uint_t u) { return __uint_as_float(u << 16); }
__device__ __forceinline__ float bfhi(uint_t u) { return __uint_as_float(u & 0xFFFF0000u); }

// LDS-only barrier: drain LDS ops, sync, fence scheduler (rule #18).
__device__ __forceinline__ void lds_barrier() {
    asm volatile("s_waitcnt lgkmcnt(0)" ::: "memory");
    __builtin_amdgcn_s_barrier();
    __builtin_amdgcn_sched_barrier(0);
}

// ---------------- prep (unchanged) ----------------
__global__ __launch_bounds__(256) void prep_kernel(
    const float* __restrict__ embed,
    const float* __restrict__ Wih_f, const float* __restrict__ b_f,
    const float* __restrict__ Wih_b, const float* __restrict__ b_b,
    const float* __restrict__ Wih_d, const float* __restrict__ b_d,
    const float* __restrict__ Whh_f, const float* __restrict__ Whh_b,
    const float* __restrict__ Whh_d,
    const float* __restrict__ attn_W, const float* __restrict__ out_W,
    const float* __restrict__ proj_W,
    float* __restrict__ ws)
{
    int i = blockIdx.x * 256 + threadIdx.x;
    if (i < XTG) {                         // dec xg gate-interleaved [v][u][g]
        int v = i >> 9, q = i & 511;
        int uu = q >> 2, g = q & 3;
        int jj = g * 128 + uu;
        float acc = b_d[jj];
        #pragma unroll
        for (int e = 0; e < 32; ++e) acc = fmaf(embed[v * 32 + e], Wih_d[jj * 32 + e], acc);
        ws[XTD + i] = acc;
    } else if (i < WTD) {                  // enc xg gate-interleaved: [d][v][u][g]
        int r = i - XTG; int d = r / 14336; int rem = r % 14336;
        int v = rem >> 9, q = rem & 511;
        int uu = q >> 2, g = q & 3;
        int jj = g * 128 + uu;
        const float* Wih = d ? Wih_b : Wih_f;
        const float* bb  = d ? b_b   : b_f;
        float acc = bb[jj];
        #pragma unroll
        for (int e = 0; e < 32; ++e) acc = fmaf(embed[v * 32 + e], Wih[jj * 32 + e], acc);
        ws[XTG + r] = acc;
    } else if (i < AWT) {
        ws[i] = 0.f;
    } else if (i < OWT) {                  // attn_WT[k][u]
        int r = i - AWT; int k = r >> 7, uu = r & 127;
        ws[i] = attn_W[uu * 256 + k];
    } else if (i < PWT) {                  // out_WT[k][v]
        int r = i - OWT; int k = r / 28, v = r % 28;
        ws[i] = out_W[v * 128 + k];
    } else if (i < WPK) {                  // projWT[k][u]
        int r = i - PWT; int k = r >> 7, uu = r & 127;
        ws[i] = proj_W[uu * 256 + k];
    } else {                               // weight frag packs (2 ushorts per thread)
        int i2 = (i - WPK) * 2;
        #pragma unroll
        for (int p = 0; p < 2; ++p, ++i2) {
            if (i2 < 131072) {             // enc pack (dirs f, b), K=128 bf16 hi
                int e  = i2 & 7;
                int ll = (i2 >> 3) & 63;
                int kt = (i2 >> 9) & 3;
                int ni = (i2 >> 11) & 3;
                int wv = (i2 >> 13) & 7;
                int d  = (i2 >> 16) & 1;
                int jj = (ni * 8 + wv) * 16 + (ll & 15);
                int kp = kt * 32 + ((ll >> 4) << 3) + e;
                const float* Whh = d ? Whh_b : Whh_f;
                ((ushort_t*)(ws + WPK))[i2] = f2bf(Whh[jj * 128 + kp]);
            } else if (i2 < 196608) {      // dec pack
                int j2 = i2 - 131072;
                int e  = j2 & 7;
                int ll = (j2 >> 3) & 63;
                int kt = (j2 >> 9) & 3;
                int ni = (j2 >> 11) & 3;
                int wv = (j2 >> 13) & 7;
                int jj = (ni * 8 + wv) * 16 + (ll & 15);
                int kp = kt * 32 + ((ll >> 4) << 3) + e;
                ((ushort_t*)(ws + WPK))[i2] = f2bf(Whh_d[jj * 128 + kp]);
            }
        }
    }
}

// ---------------- encoder: 2x-unrolled t-loop, static buffers, setprio MFMA ----------------
__global__ __launch_bounds__(512, 2) void enc_kernel(
    const int* __restrict__ src,
    const float* __restrict__ xtg_base,
    const ushort_t* __restrict__ wpk,
    float* __restrict__ hfin, float* __restrict__ cfin,
    ushort_t* __restrict__ hs)
{
    const int bx = blockIdx.x;
    const int dir = bx >> 7;
    const int b0 = (bx & 127) << 2;
    const int tid = threadIdx.x;
    const int w = tid >> 6, l = tid & 63;
    const int lg = l >> 4, col = l & 15;
    const int u = (w << 4) + col;
    const int row = lg;

    __shared__ __align__(16) ushort_t hb[2][4][144];
    __shared__ __align__(16) int tokl[256][4];

    for (int i = tid; i < 1024; i += 512)
        tokl[i >> 2][i & 3] = src[(b0 + (i & 3)) * S_ + (i >> 2)];
    for (int i = tid; i < 576; i += 512) ((uint_t*)hb)[i] = 0u;

    const float* xtg = xtg_base + dir * 14336;

    bfrag bf[4][4];
    {
        const ushort_t* wb = wpk + (((size_t)dir * 8 + w) << 13) + l * 8;
        #pragma unroll
        for (int ni = 0; ni < 4; ++ni)
            #pragma unroll
            for (int kt = 0; kt < 4; ++kt)
                bf[ni][kt] = *reinterpret_cast<const bfrag*>(wb + ((ni * 4 + kt) << 9));
    }
    __syncthreads();

    float c_reg = 0.f, h_reg = 0.f;

    f32x4 xg_cur, xg_next;
    {
        int p0 = dir ? (S_ - 1) : 0;
        xg_cur = *reinterpret_cast<const f32x4*>(xtg + ((size_t)tokl[p0][row] << 9) + (u << 2));
    }

    const bfrag zf = {0, 0, 0, 0, 0, 0, 0, 0};
    bfrag af0 = zf, af1 = zf, af2 = zf, af3 = zf;
    const bool ard = ((col & 3) == 0);
    const int ar = col >> 2;
    const int swz = ar << 3;
    const f32x4 zacc = {0.f, 0.f, 0.f, 0.f};

    // hoisted A-read / write addresses per buffer
    const ushort_t* ap0[4]; const ushort_t* ap1[4];
    #pragma unroll
    for (int kt = 0; kt < 4; ++kt) {
        int off = ((kt << 5) + (lg << 3)) ^ swz;
        ap0[kt] = &hb[0][ar][0] + off;
        ap1[kt] = &hb[1][ar][0] + off;
    }
    ushort_t* const hw0 = &hb[0][row][u ^ (row << 3)];
    ushort_t* const hw1 = &hb[1][row][u ^ (row << 3)];

    ushort_t* hs_ptr = hs + ((size_t)(b0 + row) * S_ + (dir ? (S_ - 1) : 0)) * 256
                          + dir * 128 + u;
    const int hs_step = dir ? -256 : 256;

    #define ESTEP(TT, APS, HW, XGC, XGN, DOPF) { \
        if (DOPF) { \
            int pn = dir ? (S_ - 2 - (TT)) : ((TT) + 1); \
            XGN = *reinterpret_cast<const f32x4*>(xtg + ((size_t)tokl[pn][row] << 9) + (u << 2)); \
        } \
        if (ard) { \
            af0 = *reinterpret_cast<const bfrag*>(APS[0]); \
            af1 = *reinterpret_cast<const bfrag*>(APS[1]); \
            af2 = *reinterpret_cast<const bfrag*>(APS[2]); \
            af3 = *reinterpret_cast<const bfrag*>(APS[3]); \
        } \
        __builtin_amdgcn_s_setprio(1); \
        f32x4 a0 = __builtin_amdgcn_mfma_f32_16x16x32_bf16(af0, bf[0][0], zacc, 0, 0, 0); \
        f32x4 a1 = __builtin_amdgcn_mfma_f32_16x16x32_bf16(af0, bf[1][0], zacc, 0, 0, 0); \
        f32x4 a2 = __builtin_amdgcn_mfma_f32_16x16x32_bf16(af0, bf[2][0], zacc, 0, 0, 0); \
        f32x4 a3 = __builtin_amdgcn_mfma_f32_16x16x32_bf16(af0, bf[3][0], zacc, 0, 0, 0); \
        a0 = __builtin_amdgcn_mfma_f32_16x16x32_bf16(af1, bf[0][1], a0, 0, 0, 0); \
        a1 = __builtin_amdgcn_mfma_f32_16x16x32_bf16(af1, bf[1][1], a1, 0, 0, 0); \
        a2 = __builtin_amdgcn_mfma_f32_16x16x32_bf16(af1, bf[2][1], a2, 0, 0, 0); \
        a3 = __builtin_amdgcn_mfma_f32_16x16x32_bf16(af1, bf[3][1], a3, 0, 0, 0); \
        a0 = __builtin_amdgcn_mfma_f32_16x16x32_bf16(af2, bf[0][2], a0, 0, 0, 0); \
        a1 = __builtin_amdgcn_mfma_f32_16x16x32_bf16(af2, bf[1][2], a1, 0, 0, 0); \
        a2 = __builtin_amdgcn_mfma_f32_16x16x32_bf16(af2, bf[2][2], a2, 0, 0, 0); \
        a3 = __builtin_amdgcn_mfma_f32_16x16x32_bf16(af2, bf[3][2], a3, 0, 0, 0); \
        a0 = __builtin_amdgcn_mfma_f32_16x16x32_bf16(af3, bf[0][3], a0, 0, 0, 0); \
        a1 = __builtin_amdgcn_mfma_f32_16x16x32_bf16(af3, bf[1][3], a1, 0, 0, 0); \
        a2 = __builtin_amdgcn_mfma_f32_16x16x32_bf16(af3, bf[2][3], a2, 0, 0, 0); \
        a3 = __builtin_amdgcn_mfma_f32_16x16x32_bf16(af3, bf[3][3], a3, 0, 0, 0); \
        __builtin_amdgcn_s_setprio(0); \
        { \
            float gi = a0[0] + XGC[0], gf = a1[0] + XGC[1]; \
            float gg = a2[0] + XGC[2], go = a3[0] + XGC[3]; \
            float ii = sigm(gi), ff = sigm(gf), gG = tanh_(gg), oo = sigm(go); \
            c_reg = ff * c_reg + ii * gG; \
            float h = oo * tanh_(c_reg); \
            h_reg = h; \
            ushort_t hi = f2bf(h); \
            *(HW) = hi; \
            *hs_ptr = hi; \
            hs_ptr += hs_step; \
        } \
        lds_barrier(); \
    }

    for (int t2 = 0; t2 < S_; t2 += 2) {
        ESTEP(t2,     ap0, hw1, xg_cur, xg_next, true)
        ESTEP(t2 + 1, ap1, hw0, xg_next, xg_cur, (t2 + 2 < S_))
    }
    #undef ESTEP

    hfin[dir * 65536 + (b0 + row) * 128 + u] = h_reg;
    cfin[dir * 65536 + (b0 + row) * 128 + u] = c_reg;
}

// ---------------- decoder: MFMA version (unchanged) ----------------
__global__ __launch_bounds__(512, 2) void dec_kernel(
    const int* __restrict__ target,
    const float* __restrict__ xtd_gi,
    const ushort_t* __restrict__ wpk,
    const float* __restrict__ hfin, const float* __restrict__ cfin,
    float* __restrict__ hdec)
{
    const int b0 = blockIdx.x << 2;
    const int tid = threadIdx.x;
    const int w = tid >> 6, l = tid & 63;
    const int lg = l >> 4, col = l & 15;
    const int u = (w << 4) + col;
    const int row = lg;

    __shared__ __align__(16) ushort_t hb[2][4][144];
    __shared__ __align__(16) int tokl[T_][4];

    if (tid < 40) {
        int t = tid >> 2, r = tid & 3;
        tokl[t][r] = (t == 0) ? 0 : target[(b0 + r) * T_ + t - 1];
    }

    bfrag bf[4][4];
    {
        const ushort_t* wb = wpk + 131072 + ((size_t)w << 13) + l * 8;
        #pragma unroll
        for (int ni = 0; ni < 4; ++ni)
            #pragma unroll
            for (int kt = 0; kt < 4; ++kt)
                bf[ni][kt] = *reinterpret_cast<const bfrag*>(wb + ((ni * 4 + kt) << 9));
    }

    float c_reg, h_reg;
    {
        int gb = (b0 + row) * 128 + u;
        h_reg = hfin[gb] + hfin[65536 + gb];
        c_reg = cfin[gb] + cfin[65536 + gb];
        hb[0][row][u ^ (row << 3)] = f2bf(h_reg);
    }
    __syncthreads();

    const bfrag zf = {0, 0, 0, 0, 0, 0, 0, 0};
    bfrag af0 = zf, af1 = zf, af2 = zf, af3 = zf;
    const bool ard = ((col & 3) == 0);
    const int ar = col >> 2;
    const int swz = ar << 3;
    const f32x4 zacc = {0.f, 0.f, 0.f, 0.f};

    for (int t = 0; t < T_; ++t) {
        const int cb = t & 1, nb = cb ^ 1;

        f32x4 xgc = *reinterpret_cast<const f32x4*>(
            xtd_gi + ((size_t)tokl[t][row] << 9) + (u << 2));

        if (ard) {
            const ushort_t* hp = &hb[cb][ar][0];
            af0 = *reinterpret_cast<const bfrag*>(hp + ((  0 + (lg << 3)) ^ swz));
            af1 = *reinterpret_cast<const bfrag*>(hp + (( 32 + (lg << 3)) ^ swz));
            af2 = *reinterpret_cast<const bfrag*>(hp + (( 64 + (lg << 3)) ^ swz));
            af3 = *reinterpret_cast<const bfrag*>(hp + (( 96 + (lg << 3)) ^ swz));
        }

        f32x4 a0 = __builtin_amdgcn_mfma_f32_16x16x32_bf16(af0, bf[0][0], zacc, 0, 0, 0);
        f32x4 a1 = __builtin_amdgcn_mfma_f32_16x16x32_bf16(af0, bf[1][0], zacc, 0, 0, 0);
        f32x4 a2 = __builtin_amdgcn_mfma_f32_16x16x32_bf16(af0, bf[2][0], zacc, 0, 0, 0);
        f32x4 a3 = __builtin_amdgcn_mfma_f32_16x16x32_bf16(af0, bf[3][0], zacc, 0, 0, 0);
        #define KT1(AF, kt) { \
            a0 = __builtin_amdgcn_mfma_f32_16x16x32_bf16(AF, bf[0][kt], a0, 0, 0, 0); \
            a1 = __builtin_amdgcn_mfma_f32_16x16x32_bf16(AF, bf[1][kt], a1, 0, 0, 0); \
            a2 = __builtin_amdgcn_mfma_f32_16x16x32_bf16(AF, bf[2][kt], a2, 0, 0, 0); \
            a3 = __builtin_amdgcn_mfma_f32_16x16x32_bf16(AF, bf[3][kt], a3, 0, 0, 0); \
        }
        KT1(af1, 1) KT1(af2, 2) KT1(af3, 3)
        #undef KT1

        {
            float gi = a0[0] + xgc[0], gf = a1[0] + xgc[1];
            float gg = a2[0] + xgc[2], go = a3[0] + xgc[3];
            float ii = sigm(gi), ff = sigm(gf), gG = tanh_(gg), oo = sigm(go);
            c_reg = ff * c_reg + ii * gG;
            float h = oo * tanh_(c_reg);
            h_reg = h;
            hb[nb][row][u ^ (row << 3)] = f2bf(h);
            hdec[((size_t)(b0 + row) * T_ + t) * 128 + u] = h;
        }
        lds_barrier();
    }
}

// ---------------- attention: 512 thr, e-LDS, float4 uniform reads everywhere ----------------
#define ESW(unit, row) ((((unit) ^ ((row) & 31))) << 3)   // ushort offset within row
__global__ __launch_bounds__(512, 1) void attn_kernel(
    const float* __restrict__ hdec,
    const float* __restrict__ projW, const float* __restrict__ proj_b,
    const float* __restrict__ projWT,
    const float* __restrict__ attn_WT, const float* __restrict__ attn_b,
    const float* __restrict__ out_WT, const float* __restrict__ out_b,
    const ushort_t* __restrict__ hs, float* __restrict__ out)
{
    const int b = blockIdx.x;
    const int tid = threadIdx.x;

    __shared__ __align__(16) char smem[156672];
    ushort_t* e_lds = (ushort_t*)smem;                    // [256][256] swizzled
    float* hd   = (float*)(smem + 131072);                // [10][128]
    float* q    = (float*)(smem + 136192);                // [2560]
    float* sc   = (float*)(smem + 146432);                // [2560]
    float* part = (float*)smem;                           // alias after phase 3
    float* wsum = (float*)(smem + 40960);                 // alias [12][256]

    const ushort_t* e = hs + (size_t)b * 65536;

    // issue staged e loads into regs (latency hidden under phase 0)
    uint4 st[16];
    #pragma unroll
    for (int i = 0; i < 16; ++i)
        st[i] = *reinterpret_cast<const uint4*>(e + (i * 512 + tid) * 8);

    for (int i = tid; i < 1280; i += 512) hd[i] = hdec[(size_t)b * 1280 + i];
    lds_barrier();          // hd visible; staged e loads remain in flight

    // phase 0: q[t][d]; float4 hd reads (k-unroll 4)
    {
        const int half = tid >> 8, d = tid & 255;
        float acc0 = 0.f, acc1 = 0.f, acc2 = 0.f, acc3 = 0.f, acc4 = 0.f;
        for (int k = 0; k < 128; k += 4) {
            float4 h0 = *reinterpret_cast<const float4*>(&hd[(half * 5 + 0) * 128 + k]);
            float4 h1 = *reinterpret_cast<const float4*>(&hd[(half * 5 + 1) * 128 + k]);
            float4 h2 = *reinterpret_cast<const float4*>(&hd[(half * 5 + 2) * 128 + k]);
            float4 h3 = *reinterpret_cast<const float4*>(&hd[(half * 5 + 3) * 128 + k]);
            float4 h4 = *reinterpret_cast<const float4*>(&hd[(half * 5 + 4) * 128 + k]);
            float pw0 = projW[(k + 0) * 256 + d];
            float pw1 = projW[(k + 1) * 256 + d];
            float pw2 = projW[(k + 2) * 256 + d];
            float pw3 = projW[(k + 3) * 256 + d];
            acc0 = fmaf(h0.x, pw0, acc0); acc0 = fmaf(h0.y, pw1, acc0);
            acc0 = fmaf(h0.z, pw2, acc0); acc0 = fmaf(h0.w, pw3, acc0);
            acc1 = fmaf(h1.x, pw0, acc1); acc1 = fmaf(h1.y, pw1, acc1);
            acc1 = fmaf(h1.z, pw2, acc1); acc1 = fmaf(h1.w, pw3, acc1);
            acc2 = fmaf(h2.x, pw0, acc2); acc2 = fmaf(h2.y, pw1, acc2);
            acc2 = fmaf(h2.z, pw2, acc2); acc2 = fmaf(h2.w, pw3, acc2);
            acc3 = fmaf(h3.x, pw0, acc3); acc3 = fmaf(h3.y, pw1, acc3);
            acc3 = fmaf(h3.z, pw2, acc3); acc3 = fmaf(h3.w, pw3, acc3);
            acc4 = fmaf(h4.x, pw0, acc4); acc4 = fmaf(h4.y, pw1, acc4);
            acc4 = fmaf(h4.z, pw2, acc4); acc4 = fmaf(h4.w, pw3, acc4);
        }
        int swd = d ^ ((((uint_t)d >> 5) & 7) << 2);
        q[(half * 5 + 0) * 256 + swd] = acc0;
        q[(half * 5 + 1) * 256 + swd] = acc1;
        q[(half * 5 + 2) * 256 + swd] = acc2;
        q[(half * 5 + 3) * 256 + swd] = acc3;
        q[(half * 5 + 4) * 256 + swd] = acc4;
    }

    // write staged e -> LDS (swizzled 16B units)
    #pragma unroll
    for (int i = 0; i < 16; ++i) {
        int idx = i * 512 + tid;
        int row = idx >> 5, c = idx & 31;
        *reinterpret_cast<uint4*>(e_lds + row * 256 + ESW(c, row)) = st[i];
    }
    lds_barrier();

    // phase 1: scores -- t-outer, e held in regs
    {
        const int w = tid >> 6, l = tid & 63;
        const int s3 = l >> 3, k8 = l & 7;
        uint4 E0[4], E1[4], E2[4], E3[4];
        #pragma unroll
        for (int p = 0; p < 4; ++p) {
            int s = w * 32 + p * 8 + s3;
            const ushort_t* lrow = e_lds + s * 256;
            E0[p] = *reinterpret_cast<const uint4*>(lrow + ESW((k8 << 2) + 0, s));
            E1[p] = *reinterpret_cast<const uint4*>(lrow + ESW((k8 << 2) + 1, s));
            E2[p] = *reinterpret_cast<const uint4*>(lrow + ESW((k8 << 2) + 2, s));
            E3[p] = *reinterpret_cast<const uint4*>(lrow + ESW((k8 << 2) + 3, s));
        }
        for (int t = 0; t < 10; ++t) {
            const float* qb = &q[t * 256];
            #define QCH(i) (*reinterpret_cast<const float4*>(&qb[(k8 * 32 + (i) * 4) ^ (k8 << 2)]))
            float4 Q0 = QCH(0), Q1 = QCH(1), Q2 = QCH(2), Q3 = QCH(3);
            float4 Q4 = QCH(4), Q5 = QCH(5), Q6 = QCH(6), Q7 = QCH(7);
            #undef QCH
            #pragma unroll
            for (int p = 0; p < 4; ++p) {
                float a = 0.f;
                #define DOT4(pa, pb, qv) { float4 q_ = (qv); \
                    a = fmaf(bflo(pa), q_.x, a); a = fmaf(bfhi(pa), q_.y, a); \
                    a = fmaf(bflo(pb), q_.z, a); a = fmaf(bfhi(pb), q_.w, a); }
                DOT4(E0[p].x, E0[p].y, Q0); DOT4(E0[p].z, E0[p].w, Q1);
                DOT4(E1[p].x, E1[p].y, Q2); DOT4(E1[p].z, E1[p].w, Q3);
                DOT4(E2[p].x, E2[p].y, Q4); DOT4(E2[p].z, E2[p].w, Q5);
                DOT4(E3[p].x, E3[p].y, Q6); DOT4(E3[p].z, E3[p].w, Q7);
                #undef DOT4
                a += __shfl_xor(a, 1);
                a += __shfl_xor(a, 2);
                a += __shfl_xor(a, 4);
                if (k8 == 0) sc[t * 256 + (w * 32 + p * 8 + s3)] = a;
            }
        }
    }
    __syncthreads();

    // phase 2: softmax (wave per t)
    {
        const int w = tid >> 6, l = tid & 63;
        for (int t = w; t < 10; t += 8) {
            float4 sv = *reinterpret_cast<const float4*>(&sc[t * 256 + l * 4]);
            float m = fmaxf(fmaxf(sv.x, sv.y), fmaxf(sv.z, sv.w));
            #pragma unroll
            for (int o = 1; o < 64; o <<= 1) m = fmaxf(m, __shfl_xor(m, o));
            float e0 = fast_exp2((sv.x - m) * 1.4426950408889634f);
            float e1 = fast_exp2((sv.y - m) * 1.4426950408889634f);
            float e2 = fast_exp2((sv.z - m) * 1.4426950408889634f);
            float e3 = fast_exp2((sv.w - m) * 1.4426950408889634f);
            float ssum = e0 + e1 + e2 + e3;
            #pragma unroll
            for (int o = 1; o < 64; o <<= 1) ssum += __shfl_xor(ssum, o);
            float inv = fast_rcp(ssum);
            *reinterpret_cast<float4*>(&sc[t * 256 + l * 4]) =
                make_float4(e0 * inv, e1 * inv, e2 * inv, e3 * inv);
        }
    }
    __syncthreads();

    // phase 3: wsum partials -- 4-s chunks, float4 sc reads
    {
        const int w = tid >> 6, l = tid & 63;
        const int chunk = w >> 1, tH = (w & 1) * 5;
        const int sbase = chunk * 64;
        const int unit = l >> 1, half2 = (l & 1) << 2;
        float ax[5], ay[5], az[5], aw2[5];
        #pragma unroll
        for (int i = 0; i < 5; ++i) { ax[i] = 0.f; ay[i] = 0.f; az[i] = 0.f; aw2[i] = 0.f; }
        for (int c4 = 0; c4 < 16; ++c4) {
            int s0 = sbase + c4 * 4;
            uint2 eA = *reinterpret_cast<const uint2*>(e_lds + (s0 + 0) * 256 + ESW(unit, s0 + 0) + half2);
            uint2 eB = *reinterpret_cast<const uint2*>(e_lds + (s0 + 1) * 256 + ESW(unit, s0 + 1) + half2);
            uint2 eC = *reinterpret_cast<const uint2*>(e_lds + (s0 + 2) * 256 + ESW(unit, s0 + 2) + half2);
            uint2 eD = *reinterpret_cast<const uint2*>(e_lds + (s0 + 3) * 256 + ESW(unit, s0 + 3) + half2);
            #pragma unroll
            for (int i = 0; i < 5; ++i) {
                float4 a4 = *reinterpret_cast<const float4*>(&sc[(tH + i) * 256 + s0]);
                ax[i]  = fmaf(bflo(eA.x), a4.x, ax[i]);  ay[i]  = fmaf(bfhi(eA.x), a4.x, ay[i]);
                az[i]  = fmaf(bflo(eA.y), a4.x, az[i]);  aw2[i] = fmaf(bfhi(eA.y), a4.x, aw2[i]);
                ax[i]  = fmaf(bflo(eB.x), a4.y, ax[i]);  ay[i]  = fmaf(bfhi(eB.x), a4.y, ay[i]);
                az[i]  = fmaf(bflo(eB.y), a4.y, az[i]);  aw2[i] = fmaf(bfhi(eB.y), a4.y, aw2[i]);
                ax[i]  = fmaf(bflo(eC.x), a4.z, ax[i]);  ay[i]  = fmaf(bfhi(eC.x), a4.z, ay[i]);
                az[i]  = fmaf(bflo(eC.y), a4.z, az[i]);  aw2[i] = fmaf(bfhi(eC.y), a4.z, aw2[i]);
                ax[i]  = fmaf(bflo(eD.x), a4.w, ax[i]);  ay[i]  = fmaf(bfhi(eD.x), a4.w, ay[i]);
                az[i]  = fmaf(bflo(eD.y), a4.w, az[i]);  aw2[i] = fmaf(bfhi(eD.y), a4.w, aw2[i]);
            }
        }
        __syncthreads();
        #pragma unroll
        for (int i = 0; i < 5; ++i)
            *reinterpret_cast<float4*>(&part[(chunk * 10 + tH + i) * 256 + l * 4]) =
                make_float4(ax[i], ay[i], az[i], aw2[i]);
    }
    __syncthreads();

    // phase 4: reduce partials (+zero pad rows 10,11 of wsum)
    for (int i = tid; i < 2560; i += 512)
        wsum[i] = part[i] + part[2560 + i] + part[5120 + i] + part[7680 + i];
    if (tid < 512) wsum[2560 + tid] = 0.f;
    __syncthreads();

    // phase 5+6a merged: float4 uniform reads, k-unroll 4
    {
        const int u = tid & 127, th = tid >> 7;
        const int st5 = (th < 2) ? th * 3 : 6 + (th - 2) * 2;
        const int cn = (th < 2) ? 3 : 2;
        float acc[3], accc[3];
        #pragma unroll
        for (int i = 0; i < 3; ++i) { acc[i] = proj_b[u]; accc[i] = attn_b[u]; }
        for (int k = 0; k < 128; k += 4) {
            float pw1a = projWT[(k + 0) * 128 + u];
            float pw1b = projWT[(k + 1) * 128 + u];
            float pw1c = projWT[(k + 2) * 128 + u];
            float pw1d = projWT[(k + 3) * 128 + u];
            float pw2a = projWT[(128 + k + 0) * 128 + u];
            float pw2b = projWT[(128 + k + 1) * 128 + u];
            float pw2c = projWT[(128 + k + 2) * 128 + u];
            float pw2d = projWT[(128 + k + 3) * 128 + u];
            float a1a = attn_WT[(k + 0) * 128 + u];
            float a1b = attn_WT[(k + 1) * 128 + u];
            float a1c = attn_WT[(k + 2) * 128 + u];
            float a1d = attn_WT[(k + 3) * 128 + u];
            #pragma unroll
            for (int i = 0; i < 3; ++i) {
                int tt = (st5 + i < 10) ? (st5 + i) : 9;
                float4 wlo = *reinterpret_cast<const float4*>(&wsum[(st5 + i) * 256 + k]);
                float4 whi = *reinterpret_cast<const float4*>(&wsum[(st5 + i) * 256 + 128 + k]);
                float4 hh  = *reinterpret_cast<const float4*>(&hd[tt * 128 + k]);
                acc[i] = fmaf(pw1a, wlo.x, acc[i]); acc[i] = fmaf(pw1b, wlo.y, acc[i]);
                acc[i] = fmaf(pw1c, wlo.z, acc[i]); acc[i] = fmaf(pw1d, wlo.w, acc[i]);
                acc[i] = fmaf(pw2a, whi.x, acc[i]); acc[i] = fmaf(pw2b, whi.y, acc[i]);
                acc[i] = fmaf(pw2c, whi.z, acc[i]); acc[i] = fmaf(pw2d, whi.w, acc[i]);
                accc[i] = fmaf(a1a, hh.x, accc[i]); accc[i] = fmaf(a1b, hh.y, accc[i]);
                accc[i] = fmaf(a1c, hh.z, accc[i]); accc[i] = fmaf(a1d, hh.w, accc[i]);
            }
        }
        #pragma unroll
        for (int i = 0; i < 3; ++i)
            if (i < cn) {
                q[(st5 + i) * 128 + u] = acc[i];          // ctx
                sc[(st5 + i) * 128 + u] = accc[i];        // comb partial (reuse sc)
            }
    }
    __syncthreads();

    // phase 6b: comb = tanh(partial + attn_W2 . ctx); float4 q reads
    {
        const int u = tid & 127, th = tid >> 7;
        const int st6 = (th < 2) ? th * 3 : 6 + (th - 2) * 2;
        const int cn = (th < 2) ? 3 : 2;
        float acc[3];
        #pragma unroll
        for (int i = 0; i < 3; ++i) {
            int tt = (st6 + i < 10) ? (st6 + i) : 9;
            acc[i] = sc[tt * 128 + u];
        }
        for (int k = 0; k < 128; k += 4) {
            float a2a = attn_WT[(128 + k + 0) * 128 + u];
            float a2b = attn_WT[(128 + k + 1) * 128 + u];
            float a2c = attn_WT[(128 + k + 2) * 128 + u];
            float a2d = attn_WT[(128 + k + 3) * 128 + u];
            #pragma unroll
            for (int i = 0; i < 3; ++i) {
                int tt = (st6 + i < 10) ? (st6 + i) : 9;
                float4 cc = *reinterpret_cast<const float4*>(&q[tt * 128 + k]);
                acc[i] = fmaf(a2a, cc.x, acc[i]); acc[i] = fmaf(a2b, cc.y, acc[i]);
                acc[i] = fmaf(a2c, cc.z, acc[i]); acc[i] = fmaf(a2d, cc.w, acc[i]);
            }
        }
        #pragma unroll
        for (int i = 0; i < 3; ++i)
            if (i < cn) q[1280 + (st6 + i) * 128 + u] = tanh_(acc[i]);
    }
    __syncthreads();

    // phase 7: logits; float4 q reads
    for (int o = tid; o < 280; o += 512) {
        int t = o / 28, v = o - t * 28;
        float acc = out_b[v];
        for (int k = 0; k < 128; k += 4) {
            float4 cc = *reinterpret_cast<const float4*>(&q[1280 + t * 128 + k]);
            acc = fmaf(out_WT[(k + 0) * 28 + v], cc.x, acc);
            acc = fmaf(out_WT[(k + 1) * 28 + v], cc.y, acc);
            acc = fmaf(out_WT[(k + 2) * 28 + v], cc.z, acc);
            acc = fmaf(out_WT[(k + 3) * 28 + v], cc.w, acc);
        }
        out[(size_t)b * 280 + o] = acc;
    }
}

extern "C" void kernel_launch(void* const* d_in, const int* in_sizes, int n_in,
                              void* d_out, int out_size, void* d_ws, size_t ws_size,
                              hipStream_t stream) {
    const int* src      = (const int*)d_in[0];
    const int* target   = (const int*)d_in[1];
    const float* embed  = (const float*)d_in[2];
    const float* Wih_f  = (const float*)d_in[3];
    const float* Whh_f  = (const float*)d_in[4];
    const float* b_f    = (const float*)d_in[5];
    const float* Wih_b  = (const float*)d_in[6];
    const float* Whh_b  = (const float*)d_in[7];
    const float* b_b    = (const float*)d_in[8];
    const float* Wih_d  = (const float*)d_in[9];
    const float* Whh_d  = (const float*)d_in[10];
    const float* b_d    = (const float*)d_in[11];
    const float* proj_W = (const float*)d_in[12];
    const float* proj_b = (const float*)d_in[13];
    const float* attn_W = (const float*)d_in[14];
    const float* attn_b = (const float*)d_in[15];
    const float* out_W  = (const float*)d_in[16];
    const float* out_b  = (const float*)d_in[17];

    float* ws = (float*)d_ws;
    ushort_t* hs = (ushort_t*)((char*)d_ws + HS_BYTE_OFF);
    float* out = (float*)d_out;

    prep_kernel<<<(PREP_N + 255) / 256, 256, 0, stream>>>(
        embed, Wih_f, b_f, Wih_b, b_b, Wih_d, b_d,
        Whh_f, Whh_b, Whh_d, attn_W, out_W, proj_W, ws);

    enc_kernel<<<256, 512, 0, stream>>>(
        src, ws + XTG, (const ushort_t*)(ws + WPK),
        ws + HFIN, ws + CFIN, hs);

    dec_kernel<<<128, 512, 0, stream>>>(
        target, ws + XTD, (const ushort_t*)(ws + WPK),
        ws + HFIN, ws + CFIN, ws + HDEC);

    attn_kernel<<<512, 512, 0, stream>>>(
        ws + HDEC, proj_W, proj_b, ws + PWT, ws + AWT, attn_b,
        ws + OWT, out_b, hs, out);
}